// Round 4
// baseline (12557.606 us; speedup 1.0000x reference)
//
#include <hip/hip_runtime.h>
#include <math.h>

// Model dims
#define NBLK 6
#define BS   200
#define NHID 1200
#define NINP 2400
#define TT   32
#define BZ   32
#define NTOK 16000
#define NG   4800      // NBLK*4*BS
#define ROWS 1024      // TT*BZ
#define L1D  1600      // 8 heads * 200
#define ST   (BZ*NHID) // 38400 floats per (32,1200) state

__device__ __forceinline__ float sigmoidf_(float x) { return 1.0f / (1.0f + expf(-x)); }

// ---------------------------------------------------------------------------
// 128x128-tile fp32 GEMM, 8x8 per thread. C[M,N] = A[M,K] @ B (+bias1+bias2)
// BT=false: B is (K,N) row-major. BT=true: B is (N,K) row-major.
// a_idx: optional row gather. Requires M % 128 == 0, K % 8 == 0, N % 4 == 0.
// ---------------------------------------------------------------------------
template <bool BT>
__global__ __launch_bounds__(256) void gemm128_kernel(
    const float* __restrict__ A, const float* __restrict__ B,
    const float* __restrict__ bias1, const float* __restrict__ bias2,
    float* __restrict__ C, int M, int N, int K, const int* __restrict__ a_idx)
{
    __shared__ __align__(16) float As[8][132];
    __shared__ __align__(16) float Bs[8][132];
    const int tid = threadIdx.x;
    const int tx = tid & 15, ty = tid >> 4;
    const int n0 = blockIdx.x * 128, m0 = blockIdx.y * 128;

    const int la_r = tid >> 1, la_k = (tid & 1) * 4;
    long arow;
    {
        int row = m0 + la_r;
        arow = a_idx ? (long)a_idx[row] * K : (long)row * K;
    }
    float acc[8][8] = {};

    for (int k0 = 0; k0 < K; k0 += 8) {
        {
            float4 v = *(const float4*)&A[arow + k0 + la_k];
            As[la_k + 0][la_r] = v.x;
            As[la_k + 1][la_r] = v.y;
            As[la_k + 2][la_r] = v.z;
            As[la_k + 3][la_r] = v.w;
        }
        if constexpr (!BT) {
            int kk = tid >> 5, n = (tid & 31) * 4;
            int col = n0 + n;
            float4 v = make_float4(0.f, 0.f, 0.f, 0.f);
            if (col < N) v = *(const float4*)&B[(long)(k0 + kk) * N + col];
            *(float4*)&Bs[kk][n] = v;
        } else {
            int n = tid >> 1, kk0 = (tid & 1) * 4;
            int col = n0 + n;
            float4 v = make_float4(0.f, 0.f, 0.f, 0.f);
            if (col < N) v = *(const float4*)&B[(long)col * K + k0 + kk0];
            Bs[kk0 + 0][n] = v.x;
            Bs[kk0 + 1][n] = v.y;
            Bs[kk0 + 2][n] = v.z;
            Bs[kk0 + 3][n] = v.w;
        }
        __syncthreads();
        #pragma unroll
        for (int kk = 0; kk < 8; kk++) {
            float av[8], bv[8];
            *(float4*)&av[0] = *(const float4*)&As[kk][ty * 4];
            *(float4*)&av[4] = *(const float4*)&As[kk][ty * 4 + 64];
            *(float4*)&bv[0] = *(const float4*)&Bs[kk][tx * 4];
            *(float4*)&bv[4] = *(const float4*)&Bs[kk][tx * 4 + 64];
            #pragma unroll
            for (int i = 0; i < 8; i++)
                #pragma unroll
                for (int j = 0; j < 8; j++) acc[i][j] += av[i] * bv[j];
        }
        __syncthreads();
    }
    #pragma unroll
    for (int i = 0; i < 8; i++) {
        int row = m0 + ty * 4 + (i & 3) + (i >> 2) * 64;
        #pragma unroll
        for (int jg = 0; jg < 2; jg++) {
            int col = n0 + tx * 4 + jg * 64;
            if (col < N) {
                float4 v;
                v.x = acc[i][jg * 4 + 0]; v.y = acc[i][jg * 4 + 1];
                v.z = acc[i][jg * 4 + 2]; v.w = acc[i][jg * 4 + 3];
                if (bias1) {
                    float4 b1 = *(const float4*)&bias1[col];
                    v.x += b1.x; v.y += b1.y; v.z += b1.z; v.w += b1.w;
                }
                if (bias2) {
                    float4 b2 = *(const float4*)&bias2[col];
                    v.x += b2.x; v.y += b2.y; v.z += b2.z; v.w += b2.w;
                }
                *(float4*)&C[(long)row * N + col] = v;
            }
        }
    }
}

// ---------------------------------------------------------------------------
// BigB[c'][h*200+c] = sum_d lq[c, h*200+d] * lk[c', h*200+d]   (200 x 1600)
// ---------------------------------------------------------------------------
__global__ __launch_bounds__(256) void bigb_kernel(
    const float* __restrict__ lq, const float* __restrict__ lk,
    float* __restrict__ BigB)
{
    int id = blockIdx.x * 256 + threadIdx.x;
    if (id >= 320000) return;
    int h = id / 40000, r = id % 40000, cp = r / 200, c = r % 200;
    const float4* a = (const float4*)(lq + (long)c * L1D + h * 200);
    const float4* b = (const float4*)(lk + (long)cp * L1D + h * 200);
    float s0 = 0, s1 = 0, s2 = 0, s3 = 0;
    #pragma unroll 5
    for (int d = 0; d < 50; d++) {
        float4 av = a[d], bv = b[d];
        s0 += av.x * bv.x; s1 += av.y * bv.y; s2 += av.z * bv.z; s3 += av.w * bv.w;
    }
    BigB[(long)cp * L1D + h * 200 + c] = s0 + s1 + s2 + s3;
}

// ---------------------------------------------------------------------------
// WhT[(k*200+m)*800 + g] = Wh[(k*800+g)*200 + m]  (transpose for coalesced gate dots)
// ---------------------------------------------------------------------------
__global__ __launch_bounds__(256) void whT_kernel(
    const float* __restrict__ Wh, float* __restrict__ WhT)
{
    int id = blockIdx.x * 256 + threadIdx.x;
    if (id >= 960000) return;
    int k = id / 160000, r = id % 160000, m = r / 800, g = r % 800;
    WhT[id] = Wh[(long)(k * 800 + g) * 200 + m];
}

// ---------------------------------------------------------------------------
// Small self-attention (nh=4, dk=dv=16) + residual + LN over 200, in-LDS.
// hb[1200] holds pre-attention h on entry; LN result on exit (and optionally
// written to gout). aux needs >= 2896 floats, 16B-aligned. Full block calls.
// NT = blockDim.x.
// ---------------------------------------------------------------------------
template <int NT>
__device__ __forceinline__ void att_inline(
    float* hb, float* aux, float* gout,
    const float* __restrict__ mq, const float* __restrict__ mk,
    const float* __restrict__ mv, const float* __restrict__ mfc,
    const float* __restrict__ mg, const float* __restrict__ mb)
{
    const int tid = threadIdx.x;
    float* qh   = aux;          // 384
    float* kh   = aux + 384;    // 384
    float* vh   = aux + 768;    // 384
    float* att  = aux + 1152;   // 144
    float* outp = aux + 1296;   // 384
    float* o2   = aux + 1680;   // 1200 (byte offset 6720, 16B aligned)
    float* mu_s = aux + 2880;   // 6
    float* rs_s = aux + 2888;   // 6
    if (tid < 192) {
        int which = tid >> 6, hd = tid & 63;
        const float* Mw = which == 0 ? mq : (which == 1 ? mk : mv);
        float acc[6] = {};
        for (int jx = 0; jx < 200; jx++) {
            float w = Mw[jx * 64 + hd];
            #pragma unroll
            for (int l = 0; l < 6; l++) acc[l] += hb[l * 200 + jx] * w;
        }
        float* dst = which == 0 ? qh : (which == 1 ? kh : vh);
        #pragma unroll
        for (int l = 0; l < 6; l++) dst[l * 64 + hd] = acc[l];
    }
    __syncthreads();
    if (tid < 144) {
        int h = tid / 36, r = tid % 36, q = r / 6, kk = r % 6;
        float s = 0;
        #pragma unroll
        for (int d = 0; d < 16; d++) s += qh[q * 64 + h * 16 + d] * kh[kk * 64 + h * 16 + d];
        att[(h * 6 + q) * 6 + kk] = s * 0.25f;  // 1/sqrt(16)
    }
    __syncthreads();
    if (tid < 24) {
        float* a = att + tid * 6;
        float mx = a[0];
        for (int i = 1; i < 6; i++) mx = fmaxf(mx, a[i]);
        float sm = 0;
        for (int i = 0; i < 6; i++) { a[i] = expf(a[i] - mx); sm += a[i]; }
        float inv = 1.f / sm;
        for (int i = 0; i < 6; i++) a[i] *= inv;
    }
    __syncthreads();
    for (int id = tid; id < 384; id += NT) {
        int q = id >> 6, hd = id & 63, h = hd >> 4;
        float s = 0;
        #pragma unroll
        for (int kk = 0; kk < 6; kk++) s += att[(h * 6 + q) * 6 + kk] * vh[kk * 64 + hd];
        outp[id] = s;
    }
    __syncthreads();
    if (tid < 200) {
        float acc[6] = {};
        for (int d = 0; d < 64; d++) {
            float w = mfc[d * 200 + tid];
            #pragma unroll
            for (int q = 0; q < 6; q++) acc[q] += outp[q * 64 + d] * w;
        }
        #pragma unroll
        for (int q = 0; q < 6; q++) o2[q * 200 + tid] = acc[q] + hb[q * 200 + tid];
    }
    __syncthreads();
    if (tid < 6) {
        const float4* o4 = (const float4*)(o2 + tid * 200);
        float s = 0, s2 = 0;
        for (int i = 0; i < 50; i++) {
            float4 v = o4[i];
            s += v.x + v.y + v.z + v.w;
            s2 += v.x * v.x + v.y * v.y + v.z * v.z + v.w * v.w;
        }
        float mu = s / 200.f;
        float var = s2 / 200.f - mu * mu;
        mu_s[tid] = mu;
        rs_s[tid] = 1.0f / sqrtf(var + 1e-5f);
    }
    __syncthreads();
    for (int i = tid; i < 300; i += NT) {
        int q = i / 50;
        float4 v = ((float4*)o2)[i];
        float4 g4 = ((const float4*)mg)[i % 50];
        float4 b4 = ((const float4*)mb)[i % 50];
        float mu = mu_s[q], rstd = rs_s[q];
        float4 r;
        r.x = (v.x - mu) * rstd * g4.x + b4.x;
        r.y = (v.y - mu) * rstd * g4.y + b4.y;
        r.z = (v.z - mu) * rstd * g4.z + b4.z;
        r.w = (v.w - mu) * rstd * g4.w + b4.w;
        ((float4*)hb)[i] = r;
        if (gout) ((float4*)(gout))[i] = r;
    }
    __syncthreads();
}

// ---------------------------------------------------------------------------
// Phase A: layer-0 scan, per-b independent -> 32 blocks x 1024 threads.
// Gate compute decomposed into 2400 tasks (1200 gate-quads x 2 m-halves);
// partials combined in LDS. 16 waves/block = 4/SIMD for latency hiding.
// LDS = 12000 floats (47 KB). aux for attn unions with ps.
// ---------------------------------------------------------------------------
__global__ __launch_bounds__(1024) void phaseA_kernel(
    const float* __restrict__ GX0, const float* __restrict__ h0,
    const float* __restrict__ c0, const float* __restrict__ WhT,
    float* __restrict__ out0, float* __restrict__ cf0,
    const float* __restrict__ mq, const float* __restrict__ mk,
    const float* __restrict__ mv, const float* __restrict__ mfc,
    const float* __restrict__ mg, const float* __restrict__ mb)
{
    __shared__ __align__(16) float h_s[1200];
    __shared__ __align__(16) float c_s[1200];
    __shared__ __align__(16) float g_s[4800];
    __shared__ __align__(16) float ps[4800];   // mh=1 partials; reused as attn aux
    const int b = blockIdx.x, tid = threadIdx.x;
    for (int i = tid; i < 300; i += 1024) {
        ((float4*)h_s)[i] = ((const float4*)(h0 + b * NHID))[i];
        ((float4*)c_s)[i] = ((const float4*)(c0 + b * NHID))[i];
    }
    __syncthreads();
    for (int t = 0; t < TT; t++) {
        // gates: h @ Wh^T via 2400 (quad, m-half) tasks
        for (int tau = tid; tau < 2400; tau += 1024) {
            int mh = (tau >= 1200);
            int slot = tau - mh * 1200;
            int k = slot / 200, g4 = slot - k * 200;
            const float* wp = WhT + (long)k * 160000 + (long)mh * 80000 + g4 * 4;
            const float* hp2 = h_s + k * 200 + mh * 100;
            float a0 = 0, a1 = 0, a2 = 0, a3 = 0;
            #pragma unroll 4
            for (int m = 0; m < 100; m++) {
                float hv = hp2[m];
                float4 w = *(const float4*)(wp + (long)m * 800);
                a0 += hv * w.x; a1 += hv * w.y; a2 += hv * w.z; a3 += hv * w.w;
            }
            float* dst = mh ? ps : g_s;
            int o = k * 800 + g4 * 4;
            dst[o] = a0; dst[o + 1] = a1; dst[o + 2] = a2; dst[o + 3] = a3;
        }
        __syncthreads();
        // combine + add GX + activation
        const float* gxp = GX0 + ((long)t * BZ + b) * NG;
        for (int idx = tid; idx < 1200; idx += 1024) {
            int k = idx / 200, j = idx - k * 200;
            int base = k * 800 + j;
            float gi = g_s[base]       + ps[base]       + gxp[base];
            float gf = g_s[base + 200] + ps[base + 200] + gxp[base + 200];
            float gg = g_s[base + 400] + ps[base + 400] + gxp[base + 400];
            float go = g_s[base + 600] + ps[base + 600] + gxp[base + 600];
            float cn = sigmoidf_(gf) * c_s[idx] + sigmoidf_(gi) * tanhf(gg);
            c_s[idx] = cn;
            h_s[idx] = sigmoidf_(go) * tanhf(cn);
        }
        __syncthreads();
        att_inline<1024>(h_s, ps, out0 + (long)t * ST + b * NHID, mq, mk, mv, mfc, mg, mb);
    }
    for (int i = tid; i < 300; i += 1024)
        ((float4*)(cf0 + b * NHID))[i] = ((float4*)c_s)[i];
}

// ---------------------------------------------------------------------------
// Phase B stage 1 fused: att_small on htmp (writes out1[t-1] if h==0) +
// layer-1 attention (Gram trick) for head h + PARTIAL F = attV_h @ lfc_h
// written to Fp[h] (split-K over heads; ln_sum8 combines).
// grid = 256 (b*8+h), 256 threads.
// ---------------------------------------------------------------------------
template <bool FIRST>
__global__ __launch_bounds__(256) void fusedatt_kernel(
    const float* __restrict__ htmp, const float* __restrict__ h0l1,
    float* __restrict__ out1_prev,
    const float* __restrict__ KMt, const float* __restrict__ VHt,
    const float* __restrict__ lfc, float* __restrict__ Fp,
    const float* __restrict__ mq, const float* __restrict__ mk,
    const float* __restrict__ mv, const float* __restrict__ mfc,
    const float* __restrict__ mg, const float* __restrict__ mb)
{
    __shared__ __align__(16) float hb[1200];
    __shared__ __align__(16) float aux[2896];
    __shared__ __align__(16) float a_s[1200];   // attV local: [q][m] for this head
    __shared__ float attp[72];
    __shared__ float attr[36];
    const int blk = blockIdx.x, b = blk >> 3, h = blk & 7, tid = threadIdx.x;
    if (FIRST) {
        for (int i = tid; i < 300; i += 256)
            ((float4*)hb)[i] = ((const float4*)(h0l1 + b * NHID))[i];
        __syncthreads();
    } else {
        for (int i = tid; i < 300; i += 256)
            ((float4*)hb)[i] = ((const float4*)(htmp + b * NHID))[i];
        __syncthreads();
        att_inline<256>(hb, aux, (h == 0) ? out1_prev + b * NHID : nullptr,
                        mq, mk, mv, mfc, mg, mb);
    }
    // scores[q,kk] = sum_c hb[q*200+c] * KM[(b6+kk), h*200+c]
    const float* kb = KMt + (long)b * 9600 + h * 200;
    if (tid < 72) {
        int r = tid >> 1, half = tid & 1;
        int q = r / 6, kk = r % 6;
        const float4* qr = (const float4*)(hb + q * 200 + half * 100);
        const float4* kr = (const float4*)(kb + (long)kk * L1D + half * 100);
        float s0 = 0, s1 = 0, s2 = 0, s3 = 0;
        #pragma unroll 5
        for (int d = 0; d < 25; d++) {
            float4 a = qr[d], v = kr[d];
            s0 += a.x * v.x; s1 += a.y * v.y; s2 += a.z * v.z; s3 += a.w * v.w;
        }
        attp[tid] = s0 + s1 + s2 + s3;
    }
    __syncthreads();
    if (tid < 6) {
        float v[6]; float mx = -1e30f;
        #pragma unroll
        for (int kk = 0; kk < 6; kk++) {
            float s = (attp[(tid * 6 + kk) * 2] + attp[(tid * 6 + kk) * 2 + 1]) * 0.07071067811865475f;
            v[kk] = s; mx = fmaxf(mx, s);
        }
        float sm = 0;
        #pragma unroll
        for (int kk = 0; kk < 6; kk++) { v[kk] = expf(v[kk] - mx); sm += v[kk]; }
        float inv = 1.f / sm;
        #pragma unroll
        for (int kk = 0; kk < 6; kk++) attr[tid * 6 + kk] = v[kk] * inv;
    }
    __syncthreads();
    // PV for this head's 200 dims -> a_s[q][m]
    if (tid < 200) {
        int hd = h * 200 + tid;
        const float* vb = VHt + (long)b * 9600 + hd;
        float v0 = vb[0], v1 = vb[L1D], v2 = vb[2 * L1D];
        float v3 = vb[3 * L1D], v4 = vb[4 * L1D], v5 = vb[5 * L1D];
        #pragma unroll
        for (int q = 0; q < 6; q++) {
            const float* a = attr + q * 6;
            a_s[q * 200 + tid] =
                a[0] * v0 + a[1] * v1 + a[2] * v2 + a[3] * v3 + a[4] * v4 + a[5] * v5;
        }
    }
    __syncthreads();
    // partial F: Fp[h][(b*6+q)][c] = sum_m a_s[q][m] * lfc[h*200+m][c]
    const float4* lfc4 = (const float4*)lfc;
    for (int c4 = tid; c4 < 600; c4 += 256) {
        float4 acc[6] = {};
        #pragma unroll 2
        for (int m = 0; m < 200; m++) {
            float4 w = lfc4[(long)(h * 200 + m) * 600 + c4];
            #pragma unroll
            for (int q = 0; q < 6; q++) {
                float a = a_s[q * 200 + m];
                acc[q].x += a * w.x; acc[q].y += a * w.y;
                acc[q].z += a * w.z; acc[q].w += a * w.w;
            }
        }
        #pragma unroll
        for (int q = 0; q < 6; q++)
            *(float4*)&Fp[((long)h * 192 + b * 6 + q) * NINP + c4 * 4] = acc[q];
    }
}

// ---------------------------------------------------------------------------
// Standalone att_small (for the final out1[31]). grid = 32 (b).
// ---------------------------------------------------------------------------
__global__ __launch_bounds__(256) void attsmall_kernel(
    const float* __restrict__ h_in, float* __restrict__ h_out,
    const float* __restrict__ mq, const float* __restrict__ mk,
    const float* __restrict__ mv, const float* __restrict__ mfc,
    const float* __restrict__ mg, const float* __restrict__ mb)
{
    __shared__ __align__(16) float hb[1200];
    __shared__ __align__(16) float aux[2896];
    const int b = blockIdx.x, tid = threadIdx.x;
    for (int i = tid; i < 300; i += 256)
        ((float4*)hb)[i] = ((const float4*)(h_in + b * NHID))[i];
    __syncthreads();
    att_inline<256>(hb, aux, h_out + b * NHID, mq, mk, mv, mfc, mg, mb);
}

// ---------------------------------------------------------------------------
// Sum 8 split-K partials + LayerNorm over 2400. grid = 192 rows, 256 thr.
// ---------------------------------------------------------------------------
__global__ __launch_bounds__(256) void ln_sum8_kernel(
    const float* __restrict__ Fp, float* __restrict__ Y,
    const float* __restrict__ g, const float* __restrict__ bta)
{
    __shared__ float rowbuf[2400];
    __shared__ float aw[4], bw[4];
    const int r = blockIdx.x, tid = threadIdx.x;
    const long SL = (long)192 * NINP / 4;
    const float4* f0 = (const float4*)(Fp) + (long)r * (NINP / 4);
    float s = 0, s2 = 0;
    for (int i = tid; i < 600; i += 256) {
        float4 v = f0[i];
        #pragma unroll
        for (int z = 1; z < 8; z++) {
            float4 a = f0[(long)z * SL + i];
            v.x += a.x; v.y += a.y; v.z += a.z; v.w += a.w;
        }
        ((float4*)rowbuf)[i] = v;
        s += v.x + v.y + v.z + v.w;
        s2 += v.x * v.x + v.y * v.y + v.z * v.z + v.w * v.w;
    }
    for (int off = 32; off; off >>= 1) { s += __shfl_down(s, off); s2 += __shfl_down(s2, off); }
    int wid = tid >> 6, lane = tid & 63;
    if (lane == 0) { aw[wid] = s; bw[wid] = s2; }
    __syncthreads();
    if (tid == 0) {
        float a = 0, a2 = 0;
        for (int w = 0; w < 4; w++) { a += aw[w]; a2 += bw[w]; }
        float mu = a / NINP;
        float var = a2 / NINP - mu * mu;
        aw[0] = mu;
        bw[0] = 1.0f / sqrtf(var + 1e-5f);
    }
    __syncthreads();
    float mu = aw[0], rstd = bw[0];
    for (int i = tid; i < 600; i += 256) {
        float4 v = ((float4*)rowbuf)[i];
        float4 g4 = ((const float4*)g)[i];
        float4 b4 = ((const float4*)bta)[i];
        float4 o;
        o.x = (v.x - mu) * rstd * g4.x + b4.x;
        o.y = (v.y - mu) * rstd * g4.y + b4.y;
        o.z = (v.z - mu) * rstd * g4.z + b4.z;
        o.w = (v.w - mu) * rstd * g4.w + b4.w;
        ((float4*)(Y + (long)r * NINP))[i] = o;
    }
}

// ---------------------------------------------------------------------------
// Layer-1 LSTM step: gates = inp@Wi^T + h@Wh^T + bih + bhh.
// grid (50, 6), 512 thr = (b 0..31, jg 0..3, kh 0..3). K quartered across kh,
// double-buffered x staging, LDS partial reduce.
// ---------------------------------------------------------------------------
__global__ __launch_bounds__(512) void lstm1_kernel(
    const float* __restrict__ inp, const float* __restrict__ hprev,
    float* __restrict__ c_io, const float* __restrict__ Wi,
    const float* __restrict__ Wh, const float* __restrict__ bih,
    const float* __restrict__ bhh, float* __restrict__ h_out)
{
    __shared__ float h_s[200 * 33];
    __shared__ float x_s[2][100 * 33];
    __shared__ float ps[12][128];
    const int k = blockIdx.y, jt = blockIdx.x, tid = threadIdx.x;
    const int b = tid & 31, jg = (tid >> 5) & 3, kh = tid >> 7;
    const int j = jt * 4 + jg;

    for (int idx = tid; idx < 1600; idx += 512) {
        int bb = idx / 50, m4 = idx % 50;
        float4 v = *(const float4*)&hprev[bb * NHID + k * BS + m4 * 4];
        h_s[(m4 * 4 + 0) * 33 + bb] = v.x;
        h_s[(m4 * 4 + 1) * 33 + bb] = v.y;
        h_s[(m4 * 4 + 2) * 33 + bb] = v.z;
        h_s[(m4 * 4 + 3) * 33 + bb] = v.w;
    }
    for (int idx = tid; idx < 800; idx += 512) {
        int bb = idx / 25, m4 = idx % 25;
        float4 v = *(const float4*)&inp[(long)(bb * 6 + k) * NINP + m4 * 4];
        x_s[0][(m4 * 4 + 0) * 33 + bb] = v.x;
        x_s[0][(m4 * 4 + 1) * 33 + bb] = v.y;
        x_s[0][(m4 * 4 + 2) * 33 + bb] = v.z;
        x_s[0][(m4 * 4 + 3) * 33 + bb] = v.w;
    }

    const float* wi0 = Wi + (long)(k * 800 + j) * NINP;
    const float* wi1 = wi0 + (long)200 * NINP;
    const float* wi2 = wi0 + (long)400 * NINP;
    const float* wi3 = wi0 + (long)600 * NINP;
    float a0 = 0, a1 = 0, a2 = 0, a3 = 0;
    int cur = 0;
    for (int ti = 0; ti < 24; ti++) {
        __syncthreads();
        if (ti + 1 < 24) {
            int kt = (ti + 1) * 100;
            float* xs = x_s[cur ^ 1];
            for (int idx = tid; idx < 800; idx += 512) {
                int bb = idx / 25, m4 = idx % 25;
                float4 v = *(const float4*)&inp[(long)(bb * 6 + k) * NINP + kt + m4 * 4];
                xs[(m4 * 4 + 0) * 33 + bb] = v.x;
                xs[(m4 * 4 + 1) * 33 + bb] = v.y;
                xs[(m4 * 4 + 2) * 33 + bb] = v.z;
                xs[(m4 * 4 + 3) * 33 + bb] = v.w;
            }
        }
        if (ti / 6 == kh) {
            const int kt = ti * 100;
            const float* xs = x_s[cur];
            for (int m = 0; m < 100; m += 4) {
                float4 w0 = *(const float4*)&wi0[kt + m];
                float4 w1 = *(const float4*)&wi1[kt + m];
                float4 w2 = *(const float4*)&wi2[kt + m];
                float4 w3 = *(const float4*)&wi3[kt + m];
                float x0 = xs[(m + 0) * 33 + b], x1 = xs[(m + 1) * 33 + b];
                float x2 = xs[(m + 2) * 33 + b], x3 = xs[(m + 3) * 33 + b];
                a0 += x0 * w0.x + x1 * w0.y + x2 * w0.z + x3 * w0.w;
                a1 += x0 * w1.x + x1 * w1.y + x2 * w1.z + x3 * w1.w;
                a2 += x0 * w2.x + x1 * w2.y + x2 * w2.z + x3 * w2.w;
                a3 += x0 * w3.x + x1 * w3.y + x2 * w3.z + x3 * w3.w;
            }
        }
        cur ^= 1;
    }
    if (kh == 0) {
        const float* w0 = Wh + (long)(k * 800 + j) * 200;
        const float* w1 = w0 + 200 * 200;
        const float* w2 = w0 + 400 * 200;
        const float* w3 = w0 + 600 * 200;
        for (int m = 0; m < 200; m += 4) {
            float4 wv0 = *(const float4*)&w0[m];
            float4 wv1 = *(const float4*)&w1[m];
            float4 wv2 = *(const float4*)&w2[m];
            float4 wv3 = *(const float4*)&w3[m];
            float h0v = h_s[(m + 0) * 33 + b], h1v = h_s[(m + 1) * 33 + b];
            float h2v = h_s[(m + 2) * 33 + b], h3v = h_s[(m + 3) * 33 + b];
            a0 += h0v * wv0.x + h1v * wv0.y + h2v * wv0.z + h3v * wv0.w;
            a1 += h0v * wv1.x + h1v * wv1.y + h2v * wv1.z + h3v * wv1.w;
            a2 += h0v * wv2.x + h1v * wv2.y + h2v * wv2.z + h3v * wv2.w;
            a3 += h0v * wv3.x + h1v * wv3.y + h2v * wv3.z + h3v * wv3.w;
        }
    } else {
        int g = (kh - 1) * 4, t2 = tid & 127;
        ps[g + 0][t2] = a0; ps[g + 1][t2] = a1; ps[g + 2][t2] = a2; ps[g + 3][t2] = a3;
    }
    __syncthreads();
    if (kh == 0) {
        a0 += ps[0][tid] + ps[4][tid] + ps[8][tid];
        a1 += ps[1][tid] + ps[5][tid] + ps[9][tid];
        a2 += ps[2][tid] + ps[6][tid] + ps[10][tid];
        a3 += ps[3][tid] + ps[7][tid] + ps[11][tid];
        int nb2 = k * 800;
        float gi = a0 + bih[nb2 + j] + bhh[nb2 + j];
        float gf = a1 + bih[nb2 + 200 + j] + bhh[nb2 + 200 + j];
        float gg = a2 + bih[nb2 + 400 + j] + bhh[nb2 + 400 + j];
        float go = a3 + bih[nb2 + 600 + j] + bhh[nb2 + 600 + j];
        int o = b * NHID + k * BS + j;
        float cold = c_io[o];
        float cn = sigmoidf_(gf) * cold + sigmoidf_(gi) * tanhf(gg);
        float hn = sigmoidf_(go) * tanhf(cn);
        c_io[o] = cn;
        h_out[o] = hn;
    }
}

// ---------------------------------------------------------------------------
extern "C" void kernel_launch(void* const* d_in, const int* in_sizes, int n_in,
                              void* d_out, int out_size, void* d_ws, size_t ws_size,
                              hipStream_t stream)
{
    const int*   tokens = (const int*)  d_in[0];
    const float* h0     = (const float*)d_in[1];
    const float* c0     = (const float*)d_in[2];
    const float* emb    = (const float*)d_in[3];
    const float* Wi     = (const float*)d_in[4];
    const float* Wh     = (const float*)d_in[5];
    const float* bih    = (const float*)d_in[6];
    const float* bhh    = (const float*)d_in[7];
    const float* mq     = (const float*)d_in[8];
    const float* mk     = (const float*)d_in[9];
    const float* mv     = (const float*)d_in[10];
    const float* mfc    = (const float*)d_in[11];
    const float* mg     = (const float*)d_in[12];
    const float* mb     = (const float*)d_in[13];
    const float* lq     = (const float*)d_in[14];
    const float* lk     = (const float*)d_in[15];
    const float* lv     = (const float*)d_in[16];
    const float* lfc    = (const float*)d_in[17];
    const float* lg     = (const float*)d_in[18];
    const float* lb     = (const float*)d_in[19];
    const float* dec_w  = (const float*)d_in[20];
    const float* dec_b  = (const float*)d_in[21];
    float* out = (float*)d_out;

    // workspace carve-up (floats)
    float* p = (float*)d_ws;
    float* GX0  = p; p += (long)ROWS * NG;        // 1024*4800
    float* out0 = p; p += (long)ROWS * NHID;
    float* out1 = p; p += (long)ROWS * NHID;
    float* KM   = p; p += (long)ROWS * 6 * L1D;   // 6144*1600
    float* VH1  = p; p += (long)ROWS * 6 * L1D;
    float* FCp  = p; p += (long)8 * 192 * NINP;   // split-K8 (per-head) partials
    float* inp  = p; p += 192 * NINP;
    float* htmp = p; p += BZ * NHID;
    float* cb1  = p; p += BZ * NHID;
    float* BigB = p; p += 200 * L1D;
    float* WhT  = p; p += 6 * 200 * 800;

    long off = (long)ROWS * NTOK;
    float* cf0 = out + off + 2 * ST;  // phase A writes final c directly here

    hipMemcpyAsync(cb1, c0 + ST, ST * sizeof(float), hipMemcpyDeviceToDevice, stream);

    // one-time weight prep
    bigb_kernel<<<1250, 256, 0, stream>>>(lq, lk, BigB);
    whT_kernel<<<3750, 256, 0, stream>>>(Wh, WhT);

    // GX0 = emb[tokens] @ Wi^T + bih + bhh
    gemm128_kernel<true><<<dim3(NG / 128 + 1, ROWS / 128), 256, 0, stream>>>(
        emb, Wi, bih, bhh, GX0, ROWS, NG, NINP, tokens);

    // ---- Phase A: single kernel, per-b independent scan, 1024 threads ----
    phaseA_kernel<<<BZ, 1024, 0, stream>>>(
        GX0, h0, c0, WhT, out0, cf0, mq, mk, mv, mfc, mg, mb);

    // KM = out0 @ BigB (Gram-projected keys), VH1 = out0 @ lv
    gemm128_kernel<false><<<dim3((L1D + 127) / 128, (ROWS * 6) / 128), 256, 0, stream>>>(
        out0, BigB, nullptr, nullptr, KM, ROWS * 6, L1D, BS, nullptr);
    gemm128_kernel<false><<<dim3((L1D + 127) / 128, (ROWS * 6) / 128), 256, 0, stream>>>(
        out0, lv, nullptr, nullptr, VH1, ROWS * 6, L1D, BS, nullptr);

    // ---- Phase B: 3 launches per t ----
    for (int t = 0; t < TT; t++) {
        const float* hp = (t == 0) ? h0 + ST : out1 + (long)(t - 1) * ST;
        const float* KMt = KM + (long)t * BZ * 6 * L1D;
        const float* VHt = VH1 + (long)t * BZ * 6 * L1D;
        if (t == 0) {
            fusedatt_kernel<true><<<256, 256, 0, stream>>>(
                nullptr, h0 + ST, nullptr, KMt, VHt, lfc, FCp, mq, mk, mv, mfc, mg, mb);
        } else {
            fusedatt_kernel<false><<<256, 256, 0, stream>>>(
                htmp, nullptr, out1 + (long)(t - 1) * ST, KMt, VHt, lfc, FCp,
                mq, mk, mv, mfc, mg, mb);
        }
        ln_sum8_kernel<<<192, 256, 0, stream>>>(FCp, inp, lg, lb);
        lstm1_kernel<<<dim3(50, 6), 512, 0, stream>>>(inp, hp, cb1, Wi, Wh, bih, bhh, htmp);
    }
    // final att_small -> out1[31]
    attsmall_kernel<<<BZ, 256, 0, stream>>>(htmp, out1 + (long)31 * ST, mq, mk, mv, mfc, mg, mb);

    // decode: out1 (1024,1200) @ dec_w^T + dec_b -> d_out (1024,16000)
    gemm128_kernel<true><<<dim3(NTOK / 128, ROWS / 128), 256, 0, stream>>>(
        out1, dec_w, dec_b, nullptr, out, ROWS, NTOK, NHID, nullptr);

    // final states: [hf0; hf1] then [cf0 (already written); cf1]
    hipMemcpyAsync(out + off,          out0 + (long)31 * ST, ST * sizeof(float), hipMemcpyDeviceToDevice, stream);
    hipMemcpyAsync(out + off + ST,     out1 + (long)31 * ST, ST * sizeof(float), hipMemcpyDeviceToDevice, stream);
    hipMemcpyAsync(out + off + 3 * ST, cb1,                  ST * sizeof(float), hipMemcpyDeviceToDevice, stream);
}

// Round 6
// 10996.516 us; speedup vs baseline: 1.1420x; 1.1420x over previous
//
#include <hip/hip_runtime.h>
#include <math.h>

// Model dims
#define NBLK 6
#define BS   200
#define NHID 1200
#define NINP 2400
#define TT   32
#define BZ   32
#define NTOK 16000
#define NG   4800      // NBLK*4*BS
#define ROWS 1024      // TT*BZ
#define L1D  1600      // 8 heads * 200
#define ST   (BZ*NHID) // 38400 floats per (32,1200) state

__device__ __forceinline__ float sigmoidf_(float x) { return 1.0f / (1.0f + expf(-x)); }

// ---------------------------------------------------------------------------
// 128x128-tile fp32 GEMM, 8x8 per thread. C[M,N] = A[M,K] @ B (+bias1+bias2)
// BT=false: B is (K,N) row-major. BT=true: B is (N,K) row-major.
// a_idx: optional row gather. Requires M % 128 == 0, K % 8 == 0, N % 4 == 0.
// ---------------------------------------------------------------------------
template <bool BT>
__global__ __launch_bounds__(256) void gemm128_kernel(
    const float* __restrict__ A, const float* __restrict__ B,
    const float* __restrict__ bias1, const float* __restrict__ bias2,
    float* __restrict__ C, int M, int N, int K, const int* __restrict__ a_idx)
{
    __shared__ __align__(16) float As[8][132];
    __shared__ __align__(16) float Bs[8][132];
    const int tid = threadIdx.x;
    const int tx = tid & 15, ty = tid >> 4;
    const int n0 = blockIdx.x * 128, m0 = blockIdx.y * 128;

    const int la_r = tid >> 1, la_k = (tid & 1) * 4;
    long arow;
    {
        int row = m0 + la_r;
        arow = a_idx ? (long)a_idx[row] * K : (long)row * K;
    }
    float acc[8][8] = {};

    for (int k0 = 0; k0 < K; k0 += 8) {
        {
            float4 v = *(const float4*)&A[arow + k0 + la_k];
            As[la_k + 0][la_r] = v.x;
            As[la_k + 1][la_r] = v.y;
            As[la_k + 2][la_r] = v.z;
            As[la_k + 3][la_r] = v.w;
        }
        if constexpr (!BT) {
            int kk = tid >> 5, n = (tid & 31) * 4;
            int col = n0 + n;
            float4 v = make_float4(0.f, 0.f, 0.f, 0.f);
            if (col < N) v = *(const float4*)&B[(long)(k0 + kk) * N + col];
            *(float4*)&Bs[kk][n] = v;
        } else {
            int n = tid >> 1, kk0 = (tid & 1) * 4;
            int col = n0 + n;
            float4 v = make_float4(0.f, 0.f, 0.f, 0.f);
            if (col < N) v = *(const float4*)&B[(long)col * K + k0 + kk0];
            Bs[kk0 + 0][n] = v.x;
            Bs[kk0 + 1][n] = v.y;
            Bs[kk0 + 2][n] = v.z;
            Bs[kk0 + 3][n] = v.w;
        }
        __syncthreads();
        #pragma unroll
        for (int kk = 0; kk < 8; kk++) {
            float av[8], bv[8];
            *(float4*)&av[0] = *(const float4*)&As[kk][ty * 4];
            *(float4*)&av[4] = *(const float4*)&As[kk][ty * 4 + 64];
            *(float4*)&bv[0] = *(const float4*)&Bs[kk][tx * 4];
            *(float4*)&bv[4] = *(const float4*)&Bs[kk][tx * 4 + 64];
            #pragma unroll
            for (int i = 0; i < 8; i++)
                #pragma unroll
                for (int j = 0; j < 8; j++) acc[i][j] += av[i] * bv[j];
        }
        __syncthreads();
    }
    #pragma unroll
    for (int i = 0; i < 8; i++) {
        int row = m0 + ty * 4 + (i & 3) + (i >> 2) * 64;
        #pragma unroll
        for (int jg = 0; jg < 2; jg++) {
            int col = n0 + tx * 4 + jg * 64;
            if (col < N) {
                float4 v;
                v.x = acc[i][jg * 4 + 0]; v.y = acc[i][jg * 4 + 1];
                v.z = acc[i][jg * 4 + 2]; v.w = acc[i][jg * 4 + 3];
                if (bias1) {
                    float4 b1 = *(const float4*)&bias1[col];
                    v.x += b1.x; v.y += b1.y; v.z += b1.z; v.w += b1.w;
                }
                if (bias2) {
                    float4 b2 = *(const float4*)&bias2[col];
                    v.x += b2.x; v.y += b2.y; v.z += b2.z; v.w += b2.w;
                }
                *(float4*)&C[(long)row * N + col] = v;
            }
        }
    }
}

// ---------------------------------------------------------------------------
// Batched (z) 128x128 GEMM with strides: C_z[row,col] = A_z[row,:K] @ B_z.
// A addr = A + z*a_zoff + row*a_rstride + k. B addr = B + z*b_zoff + k*N + col.
// C addr = C + z*c_zoff + row*c_rstride + col. Row-clamped A load, guarded C.
// ---------------------------------------------------------------------------
__global__ __launch_bounds__(256) void gemmz_kernel(
    const float* __restrict__ A, const float* __restrict__ B, float* __restrict__ C,
    int M, int N, int K,
    long a_rstride, long a_zoff, long b_zoff, long c_rstride, long c_zoff)
{
    __shared__ __align__(16) float As[8][132];
    __shared__ __align__(16) float Bs[8][132];
    const int tid = threadIdx.x;
    const int tx = tid & 15, ty = tid >> 4;
    const int n0 = blockIdx.x * 128, m0 = blockIdx.y * 128;
    const int z = blockIdx.z;
    const float* Az = A + a_zoff * z;
    const float* Bz = B + b_zoff * z;
    float* Cz = C + c_zoff * z;

    const int la_r = tid >> 1, la_k = (tid & 1) * 4;
    int arow_i = m0 + la_r; if (arow_i >= M) arow_i = M - 1;
    const long arow = (long)arow_i * a_rstride;
    float acc[8][8] = {};

    for (int k0 = 0; k0 < K; k0 += 8) {
        {
            float4 v = *(const float4*)&Az[arow + k0 + la_k];
            As[la_k + 0][la_r] = v.x;
            As[la_k + 1][la_r] = v.y;
            As[la_k + 2][la_r] = v.z;
            As[la_k + 3][la_r] = v.w;
        }
        {
            int kk = tid >> 5, n = (tid & 31) * 4;
            int col = n0 + n;
            float4 v = make_float4(0.f, 0.f, 0.f, 0.f);
            if (col < N) v = *(const float4*)&Bz[(long)(k0 + kk) * N + col];
            *(float4*)&Bs[kk][n] = v;
        }
        __syncthreads();
        #pragma unroll
        for (int kk = 0; kk < 8; kk++) {
            float av[8], bv[8];
            *(float4*)&av[0] = *(const float4*)&As[kk][ty * 4];
            *(float4*)&av[4] = *(const float4*)&As[kk][ty * 4 + 64];
            *(float4*)&bv[0] = *(const float4*)&Bs[kk][tx * 4];
            *(float4*)&bv[4] = *(const float4*)&Bs[kk][tx * 4 + 64];
            #pragma unroll
            for (int i = 0; i < 8; i++)
                #pragma unroll
                for (int j = 0; j < 8; j++) acc[i][j] += av[i] * bv[j];
        }
        __syncthreads();
    }
    #pragma unroll
    for (int i = 0; i < 8; i++) {
        int row = m0 + ty * 4 + (i & 3) + (i >> 2) * 64;
        if (row >= M) continue;
        #pragma unroll
        for (int jg = 0; jg < 2; jg++) {
            int col = n0 + tx * 4 + jg * 64;
            if (col < N) {
                float4 v;
                v.x = acc[i][jg * 4 + 0]; v.y = acc[i][jg * 4 + 1];
                v.z = acc[i][jg * 4 + 2]; v.w = acc[i][jg * 4 + 3];
                *(float4*)&Cz[(long)row * c_rstride + col] = v;
            }
        }
    }
}

// ---------------------------------------------------------------------------
// Split-K 64x64 GEMM (fallback path), writes partials Cp[z][M][N].
// ---------------------------------------------------------------------------
__global__ __launch_bounds__(256) void gemm_skp_kernel(
    const float* __restrict__ A, const float* __restrict__ B,
    float* __restrict__ Cp, int M, int N, int K, int KL)
{
    __shared__ __align__(16) float As[8][68];
    __shared__ __align__(16) float Bs[8][68];
    const int tid = threadIdx.x;
    const int tx = tid & 15, ty = tid >> 4;
    const int n0 = blockIdx.x * 64, m0 = blockIdx.y * 64;
    const int z = blockIdx.z;
    const int kbeg = z * KL, kend = kbeg + KL;

    float acc[4][4] = {};

    for (int k0 = kbeg; k0 < kend; k0 += 8) {
        {
            int idx = tid * 2;
            int mm = idx >> 3, kk = idx & 7;
            int row = m0 + mm;
            float2 v = *(const float2*)&A[(long)row * K + k0 + kk];
            As[kk][mm] = v.x;
            As[kk + 1][mm] = v.y;
        }
        {
            int idx = tid * 2;
            int nn = idx & 63, kk = idx >> 6;
            int n = n0 + nn;
            float2 v = make_float2(0.f, 0.f);
            if (n < N) v = *(const float2*)&B[(long)(k0 + kk) * N + n];
            Bs[kk][nn] = v.x;
            Bs[kk][nn + 1] = v.y;
        }
        __syncthreads();
        #pragma unroll
        for (int kk = 0; kk < 8; kk++) {
            const float4 a4 = *(const float4*)&As[kk][ty * 4];
            const float4 b4 = *(const float4*)&Bs[kk][tx * 4];
            const float av[4] = {a4.x, a4.y, a4.z, a4.w};
            const float bv[4] = {b4.x, b4.y, b4.z, b4.w};
            #pragma unroll
            for (int i = 0; i < 4; i++)
                #pragma unroll
                for (int j = 0; j < 4; j++) acc[i][j] += av[i] * bv[j];
        }
        __syncthreads();
    }
    float* Cz = Cp + (long)z * M * N;
    #pragma unroll
    for (int i = 0; i < 4; i++) {
        int row = m0 + ty * 4 + i;
        #pragma unroll
        for (int j = 0; j < 4; j++) {
            int col = n0 + tx * 4 + j;
            if (col < N) Cz[(long)row * N + col] = acc[i][j];
        }
    }
}

// ---------------------------------------------------------------------------
// BigB[c'][h*200+c] = sum_d lq[c, h*200+d] * lk[c', h*200+d]   (200 x 1600)
// ---------------------------------------------------------------------------
__global__ __launch_bounds__(256) void bigb_kernel(
    const float* __restrict__ lq, const float* __restrict__ lk,
    float* __restrict__ BigB)
{
    int id = blockIdx.x * 256 + threadIdx.x;
    if (id >= 320000) return;
    int h = id / 40000, r = id % 40000, cp = r / 200, c = r % 200;
    const float4* a = (const float4*)(lq + (long)c * L1D + h * 200);
    const float4* b = (const float4*)(lk + (long)cp * L1D + h * 200);
    float s0 = 0, s1 = 0, s2 = 0, s3 = 0;
    #pragma unroll 5
    for (int d = 0; d < 50; d++) {
        float4 av = a[d], bv = b[d];
        s0 += av.x * bv.x; s1 += av.y * bv.y; s2 += av.z * bv.z; s3 += av.w * bv.w;
    }
    BigB[(long)cp * L1D + h * 200 + c] = s0 + s1 + s2 + s3;
}

// ---------------------------------------------------------------------------
// WhT[(k*200+m)*800 + g] = Wh[(k*800+g)*200 + m]
// ---------------------------------------------------------------------------
__global__ __launch_bounds__(256) void whT_kernel(
    const float* __restrict__ Wh, float* __restrict__ WhT)
{
    int id = blockIdx.x * 256 + threadIdx.x;
    if (id >= 960000) return;
    int k = id / 160000, r = id % 160000, m = r / 800, g = r % 800;
    WhT[id] = Wh[(long)(k * 800 + g) * 200 + m];
}

// ---------------------------------------------------------------------------
// Small self-attention (nh=4, dk=dv=16) + residual + LN over 200, in-LDS.
// ---------------------------------------------------------------------------
template <int NT>
__device__ __forceinline__ void att_inline(
    float* hb, float* aux, float* gout,
    const float* __restrict__ mq, const float* __restrict__ mk,
    const float* __restrict__ mv, const float* __restrict__ mfc,
    const float* __restrict__ mg, const float* __restrict__ mb)
{
    const int tid = threadIdx.x;
    float* qh   = aux;          // 384
    float* kh   = aux + 384;    // 384
    float* vh   = aux + 768;    // 384
    float* att  = aux + 1152;   // 144
    float* outp = aux + 1296;   // 384
    float* o2   = aux + 1680;   // 1200
    float* mu_s = aux + 2880;   // 6
    float* rs_s = aux + 2888;   // 6
    if (tid < 192) {
        int which = tid >> 6, hd = tid & 63;
        const float* Mw = which == 0 ? mq : (which == 1 ? mk : mv);
        float acc[6] = {};
        for (int jx = 0; jx < 200; jx++) {
            float w = Mw[jx * 64 + hd];
            #pragma unroll
            for (int l = 0; l < 6; l++) acc[l] += hb[l * 200 + jx] * w;
        }
        float* dst = which == 0 ? qh : (which == 1 ? kh : vh);
        #pragma unroll
        for (int l = 0; l < 6; l++) dst[l * 64 + hd] = acc[l];
    }
    __syncthreads();
    if (tid < 144) {
        int h = tid / 36, r = tid % 36, q = r / 6, kk = r % 6;
        float s = 0;
        #pragma unroll
        for (int d = 0; d < 16; d++) s += qh[q * 64 + h * 16 + d] * kh[kk * 64 + h * 16 + d];
        att[(h * 6 + q) * 6 + kk] = s * 0.25f;
    }
    __syncthreads();
    if (tid < 24) {
        float* a = att + tid * 6;
        float mx = a[0];
        for (int i = 1; i < 6; i++) mx = fmaxf(mx, a[i]);
        float sm = 0;
        for (int i = 0; i < 6; i++) { a[i] = expf(a[i] - mx); sm += a[i]; }
        float inv = 1.f / sm;
        for (int i = 0; i < 6; i++) a[i] *= inv;
    }
    __syncthreads();
    for (int id = tid; id < 384; id += NT) {
        int q = id >> 6, hd = id & 63, h = hd >> 4;
        float s = 0;
        #pragma unroll
        for (int kk = 0; kk < 6; kk++) s += att[(h * 6 + q) * 6 + kk] * vh[kk * 64 + hd];
        outp[id] = s;
    }
    __syncthreads();
    if (tid < 200) {
        float acc[6] = {};
        for (int d = 0; d < 64; d++) {
            float w = mfc[d * 200 + tid];
            #pragma unroll
            for (int q = 0; q < 6; q++) acc[q] += outp[q * 64 + d] * w;
        }
        #pragma unroll
        for (int q = 0; q < 6; q++) o2[q * 200 + tid] = acc[q] + hb[q * 200 + tid];
    }
    __syncthreads();
    if (tid < 6) {
        const float4* o4 = (const float4*)(o2 + tid * 200);
        float s = 0, s2 = 0;
        for (int i = 0; i < 50; i++) {
            float4 v = o4[i];
            s += v.x + v.y + v.z + v.w;
            s2 += v.x * v.x + v.y * v.y + v.z * v.z + v.w * v.w;
        }
        float mu = s / 200.f;
        float var = s2 / 200.f - mu * mu;
        mu_s[tid] = mu;
        rs_s[tid] = 1.0f / sqrtf(var + 1e-5f);
    }
    __syncthreads();
    for (int i = tid; i < 300; i += NT) {
        int q = i / 50;
        float4 v = ((float4*)o2)[i];
        float4 g4 = ((const float4*)mg)[i % 50];
        float4 b4 = ((const float4*)mb)[i % 50];
        float mu = mu_s[q], rstd = rs_s[q];
        float4 r;
        r.x = (v.x - mu) * rstd * g4.x + b4.x;
        r.y = (v.y - mu) * rstd * g4.y + b4.y;
        r.z = (v.z - mu) * rstd * g4.z + b4.z;
        r.w = (v.w - mu) * rstd * g4.w + b4.w;
        ((float4*)hb)[i] = r;
        if (gout) ((float4*)(gout))[i] = r;
    }
    __syncthreads();
}

// ---------------------------------------------------------------------------
// Phase A: per-b scan, 32 blocks x 1024 thr. Dual-chain unrolled gate dots.
// ---------------------------------------------------------------------------
__global__ __launch_bounds__(1024) void phaseA_kernel(
    const float* __restrict__ GX0, const float* __restrict__ h0,
    const float* __restrict__ c0, const float* __restrict__ WhT,
    float* __restrict__ out0, float* __restrict__ cf0,
    const float* __restrict__ mq, const float* __restrict__ mk,
    const float* __restrict__ mv, const float* __restrict__ mfc,
    const float* __restrict__ mg, const float* __restrict__ mb)
{
    __shared__ __align__(16) float h_s[1200];
    __shared__ __align__(16) float c_s[1200];
    __shared__ __align__(16) float g_s[4800];
    __shared__ __align__(16) float ps[4800];
    const int b = blockIdx.x, tid = threadIdx.x;
    for (int i = tid; i < 300; i += 1024) {
        ((float4*)h_s)[i] = ((const float4*)(h0 + b * NHID))[i];
        ((float4*)c_s)[i] = ((const float4*)(c0 + b * NHID))[i];
    }
    __syncthreads();
    for (int t = 0; t < TT; t++) {
        for (int tau = tid; tau < 2400; tau += 1024) {
            int mh = (tau >= 1200);
            int slot = tau - mh * 1200;
            int k = slot / 200, g4 = slot - k * 200;
            const float* wp = WhT + (long)k * 160000 + (long)mh * 80000 + g4 * 4;
            const float* hp2 = h_s + k * 200 + mh * 100;
            float a0 = 0, a1 = 0, a2 = 0, a3 = 0;
            float e0 = 0, e1 = 0, e2 = 0, e3 = 0;
            #pragma unroll 4
            for (int m = 0; m < 100; m += 2) {
                float hv0 = hp2[m], hv1 = hp2[m + 1];
                float4 w0 = *(const float4*)(wp + (long)m * 800);
                float4 w1 = *(const float4*)(wp + (long)m * 800 + 800);
                a0 += hv0 * w0.x; a1 += hv0 * w0.y; a2 += hv0 * w0.z; a3 += hv0 * w0.w;
                e0 += hv1 * w1.x; e1 += hv1 * w1.y; e2 += hv1 * w1.z; e3 += hv1 * w1.w;
            }
            float* dst = mh ? ps : g_s;
            int o = k * 800 + g4 * 4;
            dst[o] = a0 + e0; dst[o + 1] = a1 + e1;
            dst[o + 2] = a2 + e2; dst[o + 3] = a3 + e3;
        }
        __syncthreads();
        const float* gxp = GX0 + ((long)t * BZ + b) * NG;
        for (int idx = tid; idx < 1200; idx += 1024) {
            int k = idx / 200, j = idx - k * 200;
            int base = k * 800 + j;
            float gi = g_s[base]       + ps[base]       + gxp[base];
            float gf = g_s[base + 200] + ps[base + 200] + gxp[base + 200];
            float gg = g_s[base + 400] + ps[base + 400] + gxp[base + 400];
            float go = g_s[base + 600] + ps[base + 600] + gxp[base + 600];
            float cn = sigmoidf_(gf) * c_s[idx] + sigmoidf_(gi) * tanhf(gg);
            c_s[idx] = cn;
            h_s[idx] = sigmoidf_(go) * tanhf(cn);
        }
        __syncthreads();
        att_inline<1024>(h_s, ps, out0 + (long)t * ST + b * NHID, mq, mk, mv, mfc, mg, mb);
    }
    for (int i = tid; i < 300; i += 1024)
        ((float4*)(cf0 + b * NHID))[i] = ((float4*)c_s)[i];
}

// ---------------------------------------------------------------------------
// VFh-path phase-B stage 1: att_small(htmp)->out1[t-1], scores (Gram KM),
// softmax, F = sum_{kk,h} P * VFh row, LayerNorm -> inp. grid = 32 (b), 512 thr.
// ---------------------------------------------------------------------------
template <bool FIRST>
__global__ __launch_bounds__(512) void fusedatt_vfh_kernel(
    const float* __restrict__ hraw, float* __restrict__ out1_prev,
    const float* __restrict__ KMt, const float* __restrict__ VFht,
    float* __restrict__ inp, const float* __restrict__ lg, const float* __restrict__ lbta,
    const float* __restrict__ mq, const float* __restrict__ mk,
    const float* __restrict__ mv, const float* __restrict__ mfc,
    const float* __restrict__ mg, const float* __restrict__ mb)
{
    __shared__ __align__(16) float hb[1200];
    __shared__ __align__(16) float aux[2896];
    __shared__ float attp[288];
    __shared__ float aw[8][6], bw[8][6], mu_s[6], rs_s[6];
    const int b = blockIdx.x, tid = threadIdx.x;
    for (int i = tid; i < 300; i += 512)
        ((float4*)hb)[i] = ((const float4*)(hraw + b * NHID))[i];
    __syncthreads();
    if (!FIRST)
        att_inline<512>(hb, aux, out1_prev + b * NHID, mq, mk, mv, mfc, mg, mb);

    // scores[h,q,kk] = hb[q-row] . KM[(b6+kk), h-slice]
    if (tid < 288) {
        int h = tid / 36, r = tid % 36, q = r / 6, kk = r % 6;
        const float4* qr = (const float4*)(hb + q * 200);
        const float4* kr = (const float4*)(KMt + ((long)(b * 6 + kk)) * L1D + h * 200);
        float s0 = 0, s1 = 0, s2 = 0, s3 = 0;
        #pragma unroll 5
        for (int d = 0; d < 50; d++) {
            float4 a = qr[d], v = kr[d];
            s0 += a.x * v.x; s1 += a.y * v.y; s2 += a.z * v.z; s3 += a.w * v.w;
        }
        attp[(h * 6 + q) * 6 + kk] = (s0 + s1 + s2 + s3) * 0.07071067811865475f;
    }
    __syncthreads();
    if (tid < 48) {
        float* a = attp + tid * 6;
        float mx = a[0];
        for (int i = 1; i < 6; i++) mx = fmaxf(mx, a[i]);
        float sm = 0;
        for (int i = 0; i < 6; i++) { a[i] = expf(a[i] - mx); sm += a[i]; }
        float inv = 1.f / sm;
        for (int i = 0; i < 6; i++) a[i] *= inv;
    }
    __syncthreads();

    // F accumulation: thread owns c = tid + 512*i, i<5
    float fa0[5] = {}, fa1[5] = {}, fa2[5] = {}, fa3[5] = {}, fa4[5] = {}, fa5[5] = {};
    const float* vbase = VFht + (long)b * 48 * NINP;
    #pragma unroll 1
    for (int kk = 0; kk < 6; kk++) {
        #pragma unroll 1
        for (int h = 0; h < 8; h++) {
            const float* vb = vbase + (long)(kk * 8 + h) * NINP;
            float w0 = attp[(h * 6 + 0) * 6 + kk];
            float w1 = attp[(h * 6 + 1) * 6 + kk];
            float w2 = attp[(h * 6 + 2) * 6 + kk];
            float w3 = attp[(h * 6 + 3) * 6 + kk];
            float w4 = attp[(h * 6 + 4) * 6 + kk];
            float w5 = attp[(h * 6 + 5) * 6 + kk];
            float v[5];
            #pragma unroll
            for (int i = 0; i < 5; i++) {
                int c = tid + (i << 9);
                v[i] = (c < NINP) ? vb[c] : 0.f;
            }
            #pragma unroll
            for (int i = 0; i < 5; i++) {
                fa0[i] += w0 * v[i]; fa1[i] += w1 * v[i]; fa2[i] += w2 * v[i];
                fa3[i] += w3 * v[i]; fa4[i] += w4 * v[i]; fa5[i] += w5 * v[i];
            }
        }
    }
    // LayerNorm per q-row over 2400
    {
        float s[6] = {}, s2[6] = {};
        #pragma unroll
        for (int i = 0; i < 5; i++) {
            s[0] += fa0[i]; s2[0] += fa0[i] * fa0[i];
            s[1] += fa1[i]; s2[1] += fa1[i] * fa1[i];
            s[2] += fa2[i]; s2[2] += fa2[i] * fa2[i];
            s[3] += fa3[i]; s2[3] += fa3[i] * fa3[i];
            s[4] += fa4[i]; s2[4] += fa4[i] * fa4[i];
            s[5] += fa5[i]; s2[5] += fa5[i] * fa5[i];
        }
        #pragma unroll
        for (int off = 32; off; off >>= 1) {
            #pragma unroll
            for (int q = 0; q < 6; q++) {
                s[q] += __shfl_down(s[q], off);
                s2[q] += __shfl_down(s2[q], off);
            }
        }
        int wid = tid >> 6, lane = tid & 63;
        if (lane == 0) {
            #pragma unroll
            for (int q = 0; q < 6; q++) { aw[wid][q] = s[q]; bw[wid][q] = s2[q]; }
        }
    }
    __syncthreads();
    if (tid < 6) {
        float a = 0, a2 = 0;
        #pragma unroll
        for (int w = 0; w < 8; w++) { a += aw[w][tid]; a2 += bw[w][tid]; }
        float mu = a / NINP;
        float var = a2 / NINP - mu * mu;
        mu_s[tid] = mu;
        rs_s[tid] = 1.0f / sqrtf(var + 1e-5f);
    }
    __syncthreads();
    {
        float mu0 = mu_s[0], r0 = rs_s[0], mu1 = mu_s[1], r1 = rs_s[1];
        float mu2 = mu_s[2], r2 = rs_s[2], mu3 = mu_s[3], r3 = rs_s[3];
        float mu4 = mu_s[4], r4 = rs_s[4], mu5 = mu_s[5], r5 = rs_s[5];
        #pragma unroll
        for (int i = 0; i < 5; i++) {
            int c = tid + (i << 9);
            if (c < NINP) {
                float g = lg[c], be = lbta[c];
                long rb = (long)(b * 6) * NINP + c;
                inp[rb]             = (fa0[i] - mu0) * r0 * g + be;
                inp[rb + NINP]      = (fa1[i] - mu1) * r1 * g + be;
                inp[rb + 2 * NINP]  = (fa2[i] - mu2) * r2 * g + be;
                inp[rb + 3 * NINP]  = (fa3[i] - mu3) * r3 * g + be;
                inp[rb + 4 * NINP]  = (fa4[i] - mu4) * r4 * g + be;
                inp[rb + 5 * NINP]  = (fa5[i] - mu5) * r5 * g + be;
            }
        }
    }
}

// ---------------------------------------------------------------------------
// Fallback phase-B stage 1 (round-3): att_small + Gram scores + PV -> attV.
// grid = 256 (b*8+h).
// ---------------------------------------------------------------------------
template <bool FIRST>
__global__ __launch_bounds__(256) void fusedatt_fb_kernel(
    const float* __restrict__ htmp, const float* __restrict__ h0l1,
    float* __restrict__ out1_prev,
    const float* __restrict__ KMt, const float* __restrict__ VHt,
    float* __restrict__ attV,
    const float* __restrict__ mq, const float* __restrict__ mk,
    const float* __restrict__ mv, const float* __restrict__ mfc,
    const float* __restrict__ mg, const float* __restrict__ mb)
{
    __shared__ __align__(16) float hb[1200];
    __shared__ __align__(16) float aux[2896];
    __shared__ float attp[72];
    __shared__ float attr[36];
    const int blk = blockIdx.x, b = blk >> 3, h = blk & 7, tid = threadIdx.x;
    if (FIRST) {
        for (int i = tid; i < 300; i += 256)
            ((float4*)hb)[i] = ((const float4*)(h0l1 + b * NHID))[i];
        __syncthreads();
    } else {
        for (int i = tid; i < 300; i += 256)
            ((float4*)hb)[i] = ((const float4*)(htmp + b * NHID))[i];
        __syncthreads();
        att_inline<256>(hb, aux, (h == 0) ? out1_prev + b * NHID : nullptr,
                        mq, mk, mv, mfc, mg, mb);
    }
    const float* kb = KMt + (long)b * 9600 + h * 200;
    if (tid < 72) {
        int r = tid >> 1, half = tid & 1;
        int q = r / 6, kk = r % 6;
        const float4* qr = (const float4*)(hb + q * 200 + half * 100);
        const float4* kr = (const float4*)(kb + (long)kk * L1D + half * 100);
        float s0 = 0, s1 = 0, s2 = 0, s3 = 0;
        #pragma unroll 5
        for (int d = 0; d < 25; d++) {
            float4 a = qr[d], v = kr[d];
            s0 += a.x * v.x; s1 += a.y * v.y; s2 += a.z * v.z; s3 += a.w * v.w;
        }
        attp[tid] = s0 + s1 + s2 + s3;
    }
    __syncthreads();
    if (tid < 6) {
        float v[6]; float mx = -1e30f;
        #pragma unroll
        for (int kk = 0; kk < 6; kk++) {
            float s = (attp[(tid * 6 + kk) * 2] + attp[(tid * 6 + kk) * 2 + 1]) * 0.07071067811865475f;
            v[kk] = s; mx = fmaxf(mx, s);
        }
        float sm = 0;
        #pragma unroll
        for (int kk = 0; kk < 6; kk++) { v[kk] = expf(v[kk] - mx); sm += v[kk]; }
        float inv = 1.f / sm;
        #pragma unroll
        for (int kk = 0; kk < 6; kk++) attr[tid * 6 + kk] = v[kk] * inv;
    }
    __syncthreads();
    if (tid < 200) {
        int hd = h * 200 + tid;
        const float* vb = VHt + (long)b * 9600 + hd;
        float v0 = vb[0], v1 = vb[L1D], v2 = vb[2 * L1D];
        float v3 = vb[3 * L1D], v4 = vb[4 * L1D], v5 = vb[5 * L1D];
        #pragma unroll
        for (int q = 0; q < 6; q++) {
            const float* a = attr + q * 6;
            attV[(long)b * 9600 + q * L1D + hd] =
                a[0] * v0 + a[1] * v1 + a[2] * v2 + a[3] * v3 + a[4] * v4 + a[5] * v5;
        }
    }
}

// ---------------------------------------------------------------------------
// Standalone att_small (final out1[31]). grid = 32 (b).
// ---------------------------------------------------------------------------
__global__ __launch_bounds__(256) void attsmall_kernel(
    const float* __restrict__ h_in, float* __restrict__ h_out,
    const float* __restrict__ mq, const float* __restrict__ mk,
    const float* __restrict__ mv, const float* __restrict__ mfc,
    const float* __restrict__ mg, const float* __restrict__ mb)
{
    __shared__ __align__(16) float hb[1200];
    __shared__ __align__(16) float aux[2896];
    const int b = blockIdx.x, tid = threadIdx.x;
    for (int i = tid; i < 300; i += 256)
        ((float4*)hb)[i] = ((const float4*)(h_in + b * NHID))[i];
    __syncthreads();
    att_inline<256>(hb, aux, h_out + b * NHID, mq, mk, mv, mfc, mg, mb);
}

// ---------------------------------------------------------------------------
// Sum 8 split-K partials + LayerNorm over 2400 (fallback). grid = 192.
// ---------------------------------------------------------------------------
__global__ __launch_bounds__(256) void ln_sum8_kernel(
    const float* __restrict__ Fp, float* __restrict__ Y,
    const float* __restrict__ g, const float* __restrict__ bta)
{
    __shared__ float rowbuf[2400];
    __shared__ float aw[4], bw[4];
    const int r = blockIdx.x, tid = threadIdx.x;
    const long SL = (long)192 * NINP / 4;
    const float4* f0 = (const float4*)(Fp) + (long)r * (NINP / 4);
    float s = 0, s2 = 0;
    for (int i = tid; i < 600; i += 256) {
        float4 v = f0[i];
        #pragma unroll
        for (int z = 1; z < 8; z++) {
            float4 a = f0[(long)z * SL + i];
            v.x += a.x; v.y += a.y; v.z += a.z; v.w += a.w;
        }
        ((float4*)rowbuf)[i] = v;
        s += v.x + v.y + v.z + v.w;
        s2 += v.x * v.x + v.y * v.y + v.z * v.z + v.w * v.w;
    }
    for (int off = 32; off; off >>= 1) { s += __shfl_down(s, off); s2 += __shfl_down(s2, off); }
    int wid = tid >> 6, lane = tid & 63;
    if (lane == 0) { aw[wid] = s; bw[wid] = s2; }
    __syncthreads();
    if (tid == 0) {
        float a = 0, a2 = 0;
        for (int w = 0; w < 4; w++) { a += aw[w]; a2 += bw[w]; }
        float mu = a / NINP;
        float var = a2 / NINP - mu * mu;
        aw[0] = mu;
        bw[0] = 1.0f / sqrtf(var + 1e-5f);
    }
    __syncthreads();
    float mu = aw[0], rstd = bw[0];
    for (int i = tid; i < 600; i += 256) {
        float4 v = ((float4*)rowbuf)[i];
        float4 g4 = ((const float4*)g)[i];
        float4 b4 = ((const float4*)bta)[i];
        float4 o;
        o.x = (v.x - mu) * rstd * g4.x + b4.x;
        o.y = (v.y - mu) * rstd * g4.y + b4.y;
        o.z = (v.z - mu) * rstd * g4.z + b4.z;
        o.w = (v.w - mu) * rstd * g4.w + b4.w;
        ((float4*)(Y + (long)r * NINP))[i] = o;
    }
}

// ---------------------------------------------------------------------------
// Layer-1 LSTM step: gates = inp@Wi^T + h@Wh^T + bih + bhh. grid (50,6) x 512.
// ---------------------------------------------------------------------------
__global__ __launch_bounds__(512) void lstm1_kernel(
    const float* __restrict__ inp, const float* __restrict__ hprev,
    float* __restrict__ c_io, const float* __restrict__ Wi,
    const float* __restrict__ Wh, const float* __restrict__ bih,
    const float* __restrict__ bhh, float* __restrict__ h_out)
{
    __shared__ float h_s[200 * 33];
    __shared__ float x_s[2][100 * 33];
    __shared__ float ps[12][128];
    const int k = blockIdx.y, jt = blockIdx.x, tid = threadIdx.x;
    const int b = tid & 31, jg = (tid >> 5) & 3, kh = tid >> 7;
    const int j = jt * 4 + jg;

    for (int idx = tid; idx < 1600; idx += 512) {
        int bb = idx / 50, m4 = idx % 50;
        float4 v = *(const float4*)&hprev[bb * NHID + k * BS + m4 * 4];
        h_s[(m4 * 4 + 0) * 33 + bb] = v.x;
        h_s[(m4 * 4 + 1) * 33 + bb] = v.y;
        h_s[(m4 * 4 + 2) * 33 + bb] = v.z;
        h_s[(m4 * 4 + 3) * 33 + bb] = v.w;
    }
    for (int idx = tid; idx < 800; idx += 512) {
        int bb = idx / 25, m4 = idx % 25;
        float4 v = *(const float4*)&inp[(long)(bb * 6 + k) * NINP + m4 * 4];
        x_s[0][(m4 * 4 + 0) * 33 + bb] = v.x;
        x_s[0][(m4 * 4 + 1) * 33 + bb] = v.y;
        x_s[0][(m4 * 4 + 2) * 33 + bb] = v.z;
        x_s[0][(m4 * 4 + 3) * 33 + bb] = v.w;
    }

    const float* wi0 = Wi + (long)(k * 800 + j) * NINP;
    const float* wi1 = wi0 + (long)200 * NINP;
    const float* wi2 = wi0 + (long)400 * NINP;
    const float* wi3 = wi0 + (long)600 * NINP;
    float a0 = 0, a1 = 0, a2 = 0, a3 = 0;
    int cur = 0;
    for (int ti = 0; ti < 24; ti++) {
        __syncthreads();
        if (ti + 1 < 24) {
            int kt = (ti + 1) * 100;
            float* xs = x_s[cur ^ 1];
            for (int idx = tid; idx < 800; idx += 512) {
                int bb = idx / 25, m4 = idx % 25;
                float4 v = *(const float4*)&inp[(long)(bb * 6 + k) * NINP + kt + m4 * 4];
                xs[(m4 * 4 + 0) * 33 + bb] = v.x;
                xs[(m4 * 4 + 1) * 33 + bb] = v.y;
                xs[(m4 * 4 + 2) * 33 + bb] = v.z;
                xs[(m4 * 4 + 3) * 33 + bb] = v.w;
            }
        }
        if (ti / 6 == kh) {
            const int kt = ti * 100;
            const float* xs = x_s[cur];
            for (int m = 0; m < 100; m += 4) {
                float4 w0 = *(const float4*)&wi0[kt + m];
                float4 w1 = *(const float4*)&wi1[kt + m];
                float4 w2 = *(const float4*)&wi2[kt + m];
                float4 w3 = *(const float4*)&wi3[kt + m];
                float x0 = xs[(m + 0) * 33 + b], x1 = xs[(m + 1) * 33 + b];
                float x2 = xs[(m + 2) * 33 + b], x3 = xs[(m + 3) * 33 + b];
                a0 += x0 * w0.x + x1 * w0.y + x2 * w0.z + x3 * w0.w;
                a1 += x0 * w1.x + x1 * w1.y + x2 * w1.z + x3 * w1.w;
                a2 += x0 * w2.x + x1 * w2.y + x2 * w2.z + x3 * w2.w;
                a3 += x0 * w3.x + x1 * w3.y + x2 * w3.z + x3 * w3.w;
            }
        }
        cur ^= 1;
    }
    if (kh == 0) {
        const float* w0 = Wh + (long)(k * 800 + j) * 200;
        const float* w1 = w0 + 200 * 200;
        const float* w2 = w0 + 400 * 200;
        const float* w3 = w0 + 600 * 200;
        for (int m = 0; m < 200; m += 4) {
            float4 wv0 = *(const float4*)&w0[m];
            float4 wv1 = *(const float4*)&w1[m];
            float4 wv2 = *(const float4*)&w2[m];
            float4 wv3 = *(const float4*)&w3[m];
            float h0v = h_s[(m + 0) * 33 + b], h1v = h_s[(m + 1) * 33 + b];
            float h2v = h_s[(m + 2) * 33 + b], h3v = h_s[(m + 3) * 33 + b];
            a0 += h0v * wv0.x + h1v * wv0.y + h2v * wv0.z + h3v * wv0.w;
            a1 += h0v * wv1.x + h1v * wv1.y + h2v * wv1.z + h3v * wv1.w;
            a2 += h0v * wv2.x + h1v * wv2.y + h2v * wv2.z + h3v * wv2.w;
            a3 += h0v * wv3.x + h1v * wv3.y + h2v * wv3.z + h3v * wv3.w;
        }
    } else {
        int g = (kh - 1) * 4, t2 = tid & 127;
        ps[g + 0][t2] = a0; ps[g + 1][t2] = a1; ps[g + 2][t2] = a2; ps[g + 3][t2] = a3;
    }
    __syncthreads();
    if (kh == 0) {
        a0 += ps[0][tid] + ps[4][tid] + ps[8][tid];
        a1 += ps[1][tid] + ps[5][tid] + ps[9][tid];
        a2 += ps[2][tid] + ps[6][tid] + ps[10][tid];
        a3 += ps[3][tid] + ps[7][tid] + ps[11][tid];
        int nb2 = k * 800;
        float gi = a0 + bih[nb2 + j] + bhh[nb2 + j];
        float gf = a1 + bih[nb2 + 200 + j] + bhh[nb2 + 200 + j];
        float gg = a2 + bih[nb2 + 400 + j] + bhh[nb2 + 400 + j];
        float go = a3 + bih[nb2 + 600 + j] + bhh[nb2 + 600 + j];
        int o = b * NHID + k * BS + j;
        float cold = c_io[o];
        float cn = sigmoidf_(gf) * cold + sigmoidf_(gi) * tanhf(gg);
        float hn = sigmoidf_(go) * tanhf(cn);
        c_io[o] = cn;
        h_out[o] = hn;
    }
}

// ---------------------------------------------------------------------------
extern "C" void kernel_launch(void* const* d_in, const int* in_sizes, int n_in,
                              void* d_out, int out_size, void* d_ws, size_t ws_size,
                              hipStream_t stream)
{
    const int*   tokens = (const int*)  d_in[0];
    const float* h0     = (const float*)d_in[1];
    const float* c0     = (const float*)d_in[2];
    const float* emb    = (const float*)d_in[3];
    const float* Wi     = (const float*)d_in[4];
    const float* Wh     = (const float*)d_in[5];
    const float* bih    = (const float*)d_in[6];
    const float* bhh    = (const float*)d_in[7];
    const float* mq     = (const float*)d_in[8];
    const float* mk     = (const float*)d_in[9];
    const float* mv     = (const float*)d_in[10];
    const float* mfc    = (const float*)d_in[11];
    const float* mg     = (const float*)d_in[12];
    const float* mb     = (const float*)d_in[13];
    const float* lq     = (const float*)d_in[14];
    const float* lk     = (const float*)d_in[15];
    const float* lv     = (const float*)d_in[16];
    const float* lfc    = (const float*)d_in[17];
    const float* lg     = (const float*)d_in[18];
    const float* lb     = (const float*)d_in[19];
    const float* dec_w  = (const float*)d_in[20];
    const float* dec_b  = (const float*)d_in[21];
    float* out = (float*)d_out;

    // workspace carve-up (floats) — common part
    float* p = (float*)d_ws;
    float* GX0  = p; p += (long)ROWS * NG;        // 4,915,200
    float* out0 = p; p += (long)ROWS * NHID;      // 1,228,800
    float* out1 = p; p += (long)ROWS * NHID;      // 1,228,800
    float* KM   = p; p += (long)ROWS * 6 * L1D;   // 9,830,400
    float* inp  = p; p += 192 * NINP;             // 460,800
    float* htmp = p; p += BZ * NHID;
    float* cb1  = p; p += BZ * NHID;
    float* BigB = p; p += 200 * L1D;
    float* WhT  = p; p += 6 * 200 * 800;
    long common = p - (float*)d_ws;
    const long LVF_SZ = (long)8 * 200 * NINP;          // 3,840,000
    const long VFH_SZ = (long)ROWS * 6 * 8 * NINP;     // 117,964,800
    const bool use_vfh =
        ws_size >= (size_t)(common + LVF_SZ + VFH_SZ + 1024) * sizeof(float);

    long off = (long)ROWS * NTOK;
    float* cf0 = out + off + 2 * ST;

    hipMemcpyAsync(cb1, c0 + ST, ST * sizeof(float), hipMemcpyDeviceToDevice, stream);

    bigb_kernel<<<1250, 256, 0, stream>>>(lq, lk, BigB);
    whT_kernel<<<3750, 256, 0, stream>>>(Wh, WhT);

    // GX0 = emb[tokens] @ Wi^T + bih + bhh
    gemm128_kernel<true><<<dim3(NG / 128 + 1, ROWS / 128), 256, 0, stream>>>(
        emb, Wi, bih, bhh, GX0, ROWS, NG, NINP, tokens);

    // Phase A
    phaseA_kernel<<<BZ, 1024, 0, stream>>>(
        GX0, h0, c0, WhT, out0, cf0, mq, mk, mv, mfc, mg, mb);

    // KM = out0 @ BigB (Gram-projected keys)
    gemm128_kernel<false><<<dim3((L1D + 127) / 128, (ROWS * 6) / 128), 256, 0, stream>>>(
        out0, BigB, nullptr, nullptr, KM, ROWS * 6, L1D, BS, nullptr);

    if (use_vfh) {
        float* LVF = p;
        float* VFh = p + LVF_SZ;
        // LVF[h] = lv_h (200x200 over m) @ lfc_h (200x2400)
        gemmz_kernel<<<dim3((NINP + 127) / 128, 2, 8), 256, 0, stream>>>(
            lv, lfc, LVF, 200, NINP, 200,
            (long)L1D, 200L, (long)200 * NINP, (long)NINP, (long)200 * NINP);
        // VFh[(t,b,kk), h, c] = out0 (6144x200) @ LVF[h]
        gemmz_kernel<<<dim3((NINP + 127) / 128, (ROWS * 6) / 128, 8), 256, 0, stream>>>(
            out0, LVF, VFh, ROWS * 6, NINP, 200,
            200L, 0L, (long)200 * NINP, (long)8 * NINP, (long)NINP);

        for (int t = 0; t < TT; t++) {
            const float* hp = (t == 0) ? h0 + ST : out1 + (long)(t - 1) * ST;
            const float* KMt = KM + (long)t * BZ * 6 * L1D;
            const float* VFht = VFh + (long)t * BZ * 6 * 8 * NINP;
            if (t == 0) {
                fusedatt_vfh_kernel<true><<<BZ, 512, 0, stream>>>(
                    h0 + ST, nullptr, KMt, VFht, inp, lg, lb,
                    mq, mk, mv, mfc, mg, mb);
            } else {
                fusedatt_vfh_kernel<false><<<BZ, 512, 0, stream>>>(
                    htmp, out1 + (long)(t - 1) * ST, KMt, VFht, inp, lg, lb,
                    mq, mk, mv, mfc, mg, mb);
            }
            lstm1_kernel<<<dim3(50, 6), 512, 0, stream>>>(
                inp, hp, cb1, Wi, Wh, bih, bhh, htmp);
        }
    } else {
        // fallback: round-3 proven 4-launch pipeline
        float* VH1  = p;
        float* attV = VH1 + (long)ROWS * 6 * L1D;
        float* FCp  = attV + 192 * L1D;
        gemm128_kernel<false><<<dim3((L1D + 127) / 128, (ROWS * 6) / 128), 256, 0, stream>>>(
            out0, lv, nullptr, nullptr, VH1, ROWS * 6, L1D, BS, nullptr);
        for (int t = 0; t < TT; t++) {
            const float* hp = (t == 0) ? h0 + ST : out1 + (long)(t - 1) * ST;
            const float* KMt = KM + (long)t * BZ * 6 * L1D;
            const float* VHt = VH1 + (long)t * BZ * 6 * L1D;
            if (t == 0) {
                fusedatt_fb_kernel<true><<<256, 256, 0, stream>>>(
                    nullptr, h0 + ST, nullptr, KMt, VHt, attV, mq, mk, mv, mfc, mg, mb);
            } else {
                fusedatt_fb_kernel<false><<<256, 256, 0, stream>>>(
                    htmp, nullptr, out1 + (long)(t - 1) * ST, KMt, VHt, attV,
                    mq, mk, mv, mfc, mg, mb);
            }
            gemm_skp_kernel<<<dim3((NINP + 63) / 64, 3, 8), 256, 0, stream>>>(
                attV, lfc, FCp, 192, NINP, L1D, 200);
            ln_sum8_kernel<<<192, 256, 0, stream>>>(FCp, inp, lg, lb);
            lstm1_kernel<<<dim3(50, 6), 512, 0, stream>>>(
                inp, hp, cb1, Wi, Wh, bih, bhh, htmp);
        }
    }

    attsmall_kernel<<<BZ, 256, 0, stream>>>(htmp, out1 + (long)31 * ST, mq, mk, mv, mfc, mg, mb);

    // decode
    gemm128_kernel<true><<<dim3(NTOK / 128, ROWS / 128), 256, 0, stream>>>(
        out1, dec_w, dec_b, nullptr, out, ROWS, NTOK, NHID, nullptr);

    hipMemcpyAsync(out + off,          out0 + (long)31 * ST, ST * sizeof(float), hipMemcpyDeviceToDevice, stream);
    hipMemcpyAsync(out + off + ST,     out1 + (long)31 * ST, ST * sizeof(float), hipMemcpyDeviceToDevice, stream);
    hipMemcpyAsync(out + off + 3 * ST, cb1,                  ST * sizeof(float), hipMemcpyDeviceToDevice, stream);
}

// Round 7
// 10904.390 us; speedup vs baseline: 1.1516x; 1.0084x over previous
//
#include <hip/hip_runtime.h>
#include <math.h>

// Model dims
#define NBLK 6
#define BS   200
#define NHID 1200
#define NINP 2400
#define TT   32
#define BZ   32
#define NTOK 16000
#define NG   4800      // NBLK*4*BS
#define ROWS 1024      // TT*BZ
#define L1D  1600      // 8 heads * 200
#define ST   (BZ*NHID) // 38400 floats per (32,1200) state
#define CH   2         // VFh time-chunk (timesteps per materialized chunk)

__device__ __forceinline__ float sigmoidf_(float x) { return 1.0f / (1.0f + expf(-x)); }

// ---------------------------------------------------------------------------
// 128x128-tile fp32 GEMM, 8x8 per thread. C[M,N] = A[M,K] @ B (+bias1+bias2)
// BT=false: B is (K,N) row-major. BT=true: B is (N,K) row-major.
// a_idx: optional row gather. Requires M % 128 == 0, K % 8 == 0, N % 4 == 0.
// ---------------------------------------------------------------------------
template <bool BT>
__global__ __launch_bounds__(256) void gemm128_kernel(
    const float* __restrict__ A, const float* __restrict__ B,
    const float* __restrict__ bias1, const float* __restrict__ bias2,
    float* __restrict__ C, int M, int N, int K, const int* __restrict__ a_idx)
{
    __shared__ __align__(16) float As[8][132];
    __shared__ __align__(16) float Bs[8][132];
    const int tid = threadIdx.x;
    const int tx = tid & 15, ty = tid >> 4;
    const int n0 = blockIdx.x * 128, m0 = blockIdx.y * 128;

    const int la_r = tid >> 1, la_k = (tid & 1) * 4;
    long arow;
    {
        int row = m0 + la_r;
        arow = a_idx ? (long)a_idx[row] * K : (long)row * K;
    }
    float acc[8][8] = {};

    for (int k0 = 0; k0 < K; k0 += 8) {
        {
            float4 v = *(const float4*)&A[arow + k0 + la_k];
            As[la_k + 0][la_r] = v.x;
            As[la_k + 1][la_r] = v.y;
            As[la_k + 2][la_r] = v.z;
            As[la_k + 3][la_r] = v.w;
        }
        if constexpr (!BT) {
            int kk = tid >> 5, n = (tid & 31) * 4;
            int col = n0 + n;
            float4 v = make_float4(0.f, 0.f, 0.f, 0.f);
            if (col < N) v = *(const float4*)&B[(long)(k0 + kk) * N + col];
            *(float4*)&Bs[kk][n] = v;
        } else {
            int n = tid >> 1, kk0 = (tid & 1) * 4;
            int col = n0 + n;
            float4 v = make_float4(0.f, 0.f, 0.f, 0.f);
            if (col < N) v = *(const float4*)&B[(long)col * K + k0 + kk0];
            Bs[kk0 + 0][n] = v.x;
            Bs[kk0 + 1][n] = v.y;
            Bs[kk0 + 2][n] = v.z;
            Bs[kk0 + 3][n] = v.w;
        }
        __syncthreads();
        #pragma unroll
        for (int kk = 0; kk < 8; kk++) {
            float av[8], bv[8];
            *(float4*)&av[0] = *(const float4*)&As[kk][ty * 4];
            *(float4*)&av[4] = *(const float4*)&As[kk][ty * 4 + 64];
            *(float4*)&bv[0] = *(const float4*)&Bs[kk][tx * 4];
            *(float4*)&bv[4] = *(const float4*)&Bs[kk][tx * 4 + 64];
            #pragma unroll
            for (int i = 0; i < 8; i++)
                #pragma unroll
                for (int j = 0; j < 8; j++) acc[i][j] += av[i] * bv[j];
        }
        __syncthreads();
    }
    #pragma unroll
    for (int i = 0; i < 8; i++) {
        int row = m0 + ty * 4 + (i & 3) + (i >> 2) * 64;
        #pragma unroll
        for (int jg = 0; jg < 2; jg++) {
            int col = n0 + tx * 4 + jg * 64;
            if (col < N) {
                float4 v;
                v.x = acc[i][jg * 4 + 0]; v.y = acc[i][jg * 4 + 1];
                v.z = acc[i][jg * 4 + 2]; v.w = acc[i][jg * 4 + 3];
                if (bias1) {
                    float4 b1 = *(const float4*)&bias1[col];
                    v.x += b1.x; v.y += b1.y; v.z += b1.z; v.w += b1.w;
                }
                if (bias2) {
                    float4 b2 = *(const float4*)&bias2[col];
                    v.x += b2.x; v.y += b2.y; v.z += b2.z; v.w += b2.w;
                }
                *(float4*)&C[(long)row * N + col] = v;
            }
        }
    }
}

// ---------------------------------------------------------------------------
// Batched (z) 128x128 GEMM with strides: C_z[row,col] = A_z[row,:K] @ B_z.
// A addr = A + z*a_zoff + row*a_rstride + k. B addr = B + z*b_zoff + k*N + col.
// C addr = C + z*c_zoff + row*c_rstride + col. Row-clamped A load, guarded C.
// ---------------------------------------------------------------------------
__global__ __launch_bounds__(256) void gemmz_kernel(
    const float* __restrict__ A, const float* __restrict__ B, float* __restrict__ C,
    int M, int N, int K,
    long a_rstride, long a_zoff, long b_zoff, long c_rstride, long c_zoff)
{
    __shared__ __align__(16) float As[8][132];
    __shared__ __align__(16) float Bs[8][132];
    const int tid = threadIdx.x;
    const int tx = tid & 15, ty = tid >> 4;
    const int n0 = blockIdx.x * 128, m0 = blockIdx.y * 128;
    const int z = blockIdx.z;
    const float* Az = A + a_zoff * z;
    const float* Bz = B + b_zoff * z;
    float* Cz = C + c_zoff * z;

    const int la_r = tid >> 1, la_k = (tid & 1) * 4;
    int arow_i = m0 + la_r; if (arow_i >= M) arow_i = M - 1;
    const long arow = (long)arow_i * a_rstride;
    float acc[8][8] = {};

    for (int k0 = 0; k0 < K; k0 += 8) {
        {
            float4 v = *(const float4*)&Az[arow + k0 + la_k];
            As[la_k + 0][la_r] = v.x;
            As[la_k + 1][la_r] = v.y;
            As[la_k + 2][la_r] = v.z;
            As[la_k + 3][la_r] = v.w;
        }
        {
            int kk = tid >> 5, n = (tid & 31) * 4;
            int col = n0 + n;
            float4 v = make_float4(0.f, 0.f, 0.f, 0.f);
            if (col < N) v = *(const float4*)&Bz[(long)(k0 + kk) * N + col];
            *(float4*)&Bs[kk][n] = v;
        }
        __syncthreads();
        #pragma unroll
        for (int kk = 0; kk < 8; kk++) {
            float av[8], bv[8];
            *(float4*)&av[0] = *(const float4*)&As[kk][ty * 4];
            *(float4*)&av[4] = *(const float4*)&As[kk][ty * 4 + 64];
            *(float4*)&bv[0] = *(const float4*)&Bs[kk][tx * 4];
            *(float4*)&bv[4] = *(const float4*)&Bs[kk][tx * 4 + 64];
            #pragma unroll
            for (int i = 0; i < 8; i++)
                #pragma unroll
                for (int j = 0; j < 8; j++) acc[i][j] += av[i] * bv[j];
        }
        __syncthreads();
    }
    #pragma unroll
    for (int i = 0; i < 8; i++) {
        int row = m0 + ty * 4 + (i & 3) + (i >> 2) * 64;
        if (row >= M) continue;
        #pragma unroll
        for (int jg = 0; jg < 2; jg++) {
            int col = n0 + tx * 4 + jg * 64;
            if (col < N) {
                float4 v;
                v.x = acc[i][jg * 4 + 0]; v.y = acc[i][jg * 4 + 1];
                v.z = acc[i][jg * 4 + 2]; v.w = acc[i][jg * 4 + 3];
                *(float4*)&Cz[(long)row * c_rstride + col] = v;
            }
        }
    }
}

// ---------------------------------------------------------------------------
// Split-K 64x64 GEMM (fallback path), writes partials Cp[z][M][N].
// ---------------------------------------------------------------------------
__global__ __launch_bounds__(256) void gemm_skp_kernel(
    const float* __restrict__ A, const float* __restrict__ B,
    float* __restrict__ Cp, int M, int N, int K, int KL)
{
    __shared__ __align__(16) float As[8][68];
    __shared__ __align__(16) float Bs[8][68];
    const int tid = threadIdx.x;
    const int tx = tid & 15, ty = tid >> 4;
    const int n0 = blockIdx.x * 64, m0 = blockIdx.y * 64;
    const int z = blockIdx.z;
    const int kbeg = z * KL, kend = kbeg + KL;

    float acc[4][4] = {};

    for (int k0 = kbeg; k0 < kend; k0 += 8) {
        {
            int idx = tid * 2;
            int mm = idx >> 3, kk = idx & 7;
            int row = m0 + mm;
            float2 v = *(const float2*)&A[(long)row * K + k0 + kk];
            As[kk][mm] = v.x;
            As[kk + 1][mm] = v.y;
        }
        {
            int idx = tid * 2;
            int nn = idx & 63, kk = idx >> 6;
            int n = n0 + nn;
            float2 v = make_float2(0.f, 0.f);
            if (n < N) v = *(const float2*)&B[(long)(k0 + kk) * N + n];
            Bs[kk][nn] = v.x;
            Bs[kk][nn + 1] = v.y;
        }
        __syncthreads();
        #pragma unroll
        for (int kk = 0; kk < 8; kk++) {
            const float4 a4 = *(const float4*)&As[kk][ty * 4];
            const float4 b4 = *(const float4*)&Bs[kk][tx * 4];
            const float av[4] = {a4.x, a4.y, a4.z, a4.w};
            const float bv[4] = {b4.x, b4.y, b4.z, b4.w};
            #pragma unroll
            for (int i = 0; i < 4; i++)
                #pragma unroll
                for (int j = 0; j < 4; j++) acc[i][j] += av[i] * bv[j];
        }
        __syncthreads();
    }
    float* Cz = Cp + (long)z * M * N;
    #pragma unroll
    for (int i = 0; i < 4; i++) {
        int row = m0 + ty * 4 + i;
        #pragma unroll
        for (int j = 0; j < 4; j++) {
            int col = n0 + tx * 4 + j;
            if (col < N) Cz[(long)row * N + col] = acc[i][j];
        }
    }
}

// ---------------------------------------------------------------------------
// BigB[c'][h*200+c] = sum_d lq[c, h*200+d] * lk[c', h*200+d]   (200 x 1600)
// ---------------------------------------------------------------------------
__global__ __launch_bounds__(256) void bigb_kernel(
    const float* __restrict__ lq, const float* __restrict__ lk,
    float* __restrict__ BigB)
{
    int id = blockIdx.x * 256 + threadIdx.x;
    if (id >= 320000) return;
    int h = id / 40000, r = id % 40000, cp = r / 200, c = r % 200;
    const float4* a = (const float4*)(lq + (long)c * L1D + h * 200);
    const float4* b = (const float4*)(lk + (long)cp * L1D + h * 200);
    float s0 = 0, s1 = 0, s2 = 0, s3 = 0;
    #pragma unroll 5
    for (int d = 0; d < 50; d++) {
        float4 av = a[d], bv = b[d];
        s0 += av.x * bv.x; s1 += av.y * bv.y; s2 += av.z * bv.z; s3 += av.w * bv.w;
    }
    BigB[(long)cp * L1D + h * 200 + c] = s0 + s1 + s2 + s3;
}

// ---------------------------------------------------------------------------
// WhT[(k*200+m)*800 + g] = Wh[(k*800+g)*200 + m]
// ---------------------------------------------------------------------------
__global__ __launch_bounds__(256) void whT_kernel(
    const float* __restrict__ Wh, float* __restrict__ WhT)
{
    int id = blockIdx.x * 256 + threadIdx.x;
    if (id >= 960000) return;
    int k = id / 160000, r = id % 160000, m = r / 800, g = r % 800;
    WhT[id] = Wh[(long)(k * 800 + g) * 200 + m];
}

// ---------------------------------------------------------------------------
// Small self-attention (nh=4, dk=dv=16) + residual + LN over 200, in-LDS.
// ---------------------------------------------------------------------------
template <int NT>
__device__ __forceinline__ void att_inline(
    float* hb, float* aux, float* gout,
    const float* __restrict__ mq, const float* __restrict__ mk,
    const float* __restrict__ mv, const float* __restrict__ mfc,
    const float* __restrict__ mg, const float* __restrict__ mb)
{
    const int tid = threadIdx.x;
    float* qh   = aux;          // 384
    float* kh   = aux + 384;    // 384
    float* vh   = aux + 768;    // 384
    float* att  = aux + 1152;   // 144
    float* outp = aux + 1296;   // 384
    float* o2   = aux + 1680;   // 1200
    float* mu_s = aux + 2880;   // 6
    float* rs_s = aux + 2888;   // 6
    if (tid < 192) {
        int which = tid >> 6, hd = tid & 63;
        const float* Mw = which == 0 ? mq : (which == 1 ? mk : mv);
        float acc[6] = {};
        for (int jx = 0; jx < 200; jx++) {
            float w = Mw[jx * 64 + hd];
            #pragma unroll
            for (int l = 0; l < 6; l++) acc[l] += hb[l * 200 + jx] * w;
        }
        float* dst = which == 0 ? qh : (which == 1 ? kh : vh);
        #pragma unroll
        for (int l = 0; l < 6; l++) dst[l * 64 + hd] = acc[l];
    }
    __syncthreads();
    if (tid < 144) {
        int h = tid / 36, r = tid % 36, q = r / 6, kk = r % 6;
        float s = 0;
        #pragma unroll
        for (int d = 0; d < 16; d++) s += qh[q * 64 + h * 16 + d] * kh[kk * 64 + h * 16 + d];
        att[(h * 6 + q) * 6 + kk] = s * 0.25f;
    }
    __syncthreads();
    if (tid < 24) {
        float* a = att + tid * 6;
        float mx = a[0];
        for (int i = 1; i < 6; i++) mx = fmaxf(mx, a[i]);
        float sm = 0;
        for (int i = 0; i < 6; i++) { a[i] = expf(a[i] - mx); sm += a[i]; }
        float inv = 1.f / sm;
        for (int i = 0; i < 6; i++) a[i] *= inv;
    }
    __syncthreads();
    for (int id = tid; id < 384; id += NT) {
        int q = id >> 6, hd = id & 63, h = hd >> 4;
        float s = 0;
        #pragma unroll
        for (int kk = 0; kk < 6; kk++) s += att[(h * 6 + q) * 6 + kk] * vh[kk * 64 + hd];
        outp[id] = s;
    }
    __syncthreads();
    if (tid < 200) {
        float acc[6] = {};
        for (int d = 0; d < 64; d++) {
            float w = mfc[d * 200 + tid];
            #pragma unroll
            for (int q = 0; q < 6; q++) acc[q] += outp[q * 64 + d] * w;
        }
        #pragma unroll
        for (int q = 0; q < 6; q++) o2[q * 200 + tid] = acc[q] + hb[q * 200 + tid];
    }
    __syncthreads();
    if (tid < 6) {
        const float4* o4 = (const float4*)(o2 + tid * 200);
        float s = 0, s2 = 0;
        for (int i = 0; i < 50; i++) {
            float4 v = o4[i];
            s += v.x + v.y + v.z + v.w;
            s2 += v.x * v.x + v.y * v.y + v.z * v.z + v.w * v.w;
        }
        float mu = s / 200.f;
        float var = s2 / 200.f - mu * mu;
        mu_s[tid] = mu;
        rs_s[tid] = 1.0f / sqrtf(var + 1e-5f);
    }
    __syncthreads();
    for (int i = tid; i < 300; i += NT) {
        int q = i / 50;
        float4 v = ((float4*)o2)[i];
        float4 g4 = ((const float4*)mg)[i % 50];
        float4 b4 = ((const float4*)mb)[i % 50];
        float mu = mu_s[q], rstd = rs_s[q];
        float4 r;
        r.x = (v.x - mu) * rstd * g4.x + b4.x;
        r.y = (v.y - mu) * rstd * g4.y + b4.y;
        r.z = (v.z - mu) * rstd * g4.z + b4.z;
        r.w = (v.w - mu) * rstd * g4.w + b4.w;
        ((float4*)hb)[i] = r;
        if (gout) ((float4*)(gout))[i] = r;
    }
    __syncthreads();
}

// ---------------------------------------------------------------------------
// Phase A: per-b scan, 32 blocks x 1024 thr. Dual-chain unrolled gate dots.
// ---------------------------------------------------------------------------
__global__ __launch_bounds__(1024) void phaseA_kernel(
    const float* __restrict__ GX0, const float* __restrict__ h0,
    const float* __restrict__ c0, const float* __restrict__ WhT,
    float* __restrict__ out0, float* __restrict__ cf0,
    const float* __restrict__ mq, const float* __restrict__ mk,
    const float* __restrict__ mv, const float* __restrict__ mfc,
    const float* __restrict__ mg, const float* __restrict__ mb)
{
    __shared__ __align__(16) float h_s[1200];
    __shared__ __align__(16) float c_s[1200];
    __shared__ __align__(16) float g_s[4800];
    __shared__ __align__(16) float ps[4800];
    const int b = blockIdx.x, tid = threadIdx.x;
    for (int i = tid; i < 300; i += 1024) {
        ((float4*)h_s)[i] = ((const float4*)(h0 + b * NHID))[i];
        ((float4*)c_s)[i] = ((const float4*)(c0 + b * NHID))[i];
    }
    __syncthreads();
    for (int t = 0; t < TT; t++) {
        for (int tau = tid; tau < 2400; tau += 1024) {
            int mh = (tau >= 1200);
            int slot = tau - mh * 1200;
            int k = slot / 200, g4 = slot - k * 200;
            const float* wp = WhT + (long)k * 160000 + (long)mh * 80000 + g4 * 4;
            const float* hp2 = h_s + k * 200 + mh * 100;
            float a0 = 0, a1 = 0, a2 = 0, a3 = 0;
            float e0 = 0, e1 = 0, e2 = 0, e3 = 0;
            #pragma unroll 4
            for (int m = 0; m < 100; m += 2) {
                float hv0 = hp2[m], hv1 = hp2[m + 1];
                float4 w0 = *(const float4*)(wp + (long)m * 800);
                float4 w1 = *(const float4*)(wp + (long)m * 800 + 800);
                a0 += hv0 * w0.x; a1 += hv0 * w0.y; a2 += hv0 * w0.z; a3 += hv0 * w0.w;
                e0 += hv1 * w1.x; e1 += hv1 * w1.y; e2 += hv1 * w1.z; e3 += hv1 * w1.w;
            }
            float* dst = mh ? ps : g_s;
            int o = k * 800 + g4 * 4;
            dst[o] = a0 + e0; dst[o + 1] = a1 + e1;
            dst[o + 2] = a2 + e2; dst[o + 3] = a3 + e3;
        }
        __syncthreads();
        const float* gxp = GX0 + ((long)t * BZ + b) * NG;
        for (int idx = tid; idx < 1200; idx += 1024) {
            int k = idx / 200, j = idx - k * 200;
            int base = k * 800 + j;
            float gi = g_s[base]       + ps[base]       + gxp[base];
            float gf = g_s[base + 200] + ps[base + 200] + gxp[base + 200];
            float gg = g_s[base + 400] + ps[base + 400] + gxp[base + 400];
            float go = g_s[base + 600] + ps[base + 600] + gxp[base + 600];
            float cn = sigmoidf_(gf) * c_s[idx] + sigmoidf_(gi) * tanhf(gg);
            c_s[idx] = cn;
            h_s[idx] = sigmoidf_(go) * tanhf(cn);
        }
        __syncthreads();
        att_inline<1024>(h_s, ps, out0 + (long)t * ST + b * NHID, mq, mk, mv, mfc, mg, mb);
    }
    for (int i = tid; i < 300; i += 1024)
        ((float4*)(cf0 + b * NHID))[i] = ((float4*)c_s)[i];
}

// ---------------------------------------------------------------------------
// VFh-path phase-B stage 1: att_small(htmp)->out1[t-1], scores (Gram KM),
// softmax, F = sum_{kk,h} P * VFh row, LayerNorm -> inp. grid = 32 (b), 512 thr.
// ---------------------------------------------------------------------------
template <bool FIRST>
__global__ __launch_bounds__(512) void fusedatt_vfh_kernel(
    const float* __restrict__ hraw, float* __restrict__ out1_prev,
    const float* __restrict__ KMt, const float* __restrict__ VFht,
    float* __restrict__ inp, const float* __restrict__ lg, const float* __restrict__ lbta,
    const float* __restrict__ mq, const float* __restrict__ mk,
    const float* __restrict__ mv, const float* __restrict__ mfc,
    const float* __restrict__ mg, const float* __restrict__ mb)
{
    __shared__ __align__(16) float hb[1200];
    __shared__ __align__(16) float aux[2896];
    __shared__ float attp[288];
    __shared__ float aw[8][6], bw[8][6], mu_s[6], rs_s[6];
    const int b = blockIdx.x, tid = threadIdx.x;
    for (int i = tid; i < 300; i += 512)
        ((float4*)hb)[i] = ((const float4*)(hraw + b * NHID))[i];
    __syncthreads();
    if (!FIRST)
        att_inline<512>(hb, aux, out1_prev + b * NHID, mq, mk, mv, mfc, mg, mb);

    // scores[h,q,kk] = hb[q-row] . KM[(b6+kk), h-slice]
    if (tid < 288) {
        int h = tid / 36, r = tid % 36, q = r / 6, kk = r % 6;
        const float4* qr = (const float4*)(hb + q * 200);
        const float4* kr = (const float4*)(KMt + ((long)(b * 6 + kk)) * L1D + h * 200);
        float s0 = 0, s1 = 0, s2 = 0, s3 = 0;
        #pragma unroll 5
        for (int d = 0; d < 50; d++) {
            float4 a = qr[d], v = kr[d];
            s0 += a.x * v.x; s1 += a.y * v.y; s2 += a.z * v.z; s3 += a.w * v.w;
        }
        attp[(h * 6 + q) * 6 + kk] = (s0 + s1 + s2 + s3) * 0.07071067811865475f;
    }
    __syncthreads();
    if (tid < 48) {
        float* a = attp + tid * 6;
        float mx = a[0];
        for (int i = 1; i < 6; i++) mx = fmaxf(mx, a[i]);
        float sm = 0;
        for (int i = 0; i < 6; i++) { a[i] = expf(a[i] - mx); sm += a[i]; }
        float inv = 1.f / sm;
        for (int i = 0; i < 6; i++) a[i] *= inv;
    }
    __syncthreads();

    // F accumulation: thread owns c = tid + 512*i, i<5
    float fa0[5] = {}, fa1[5] = {}, fa2[5] = {}, fa3[5] = {}, fa4[5] = {}, fa5[5] = {};
    const float* vbase = VFht + (long)b * 48 * NINP;
    #pragma unroll 1
    for (int kk = 0; kk < 6; kk++) {
        #pragma unroll 1
        for (int h = 0; h < 8; h++) {
            const float* vb = vbase + (long)(kk * 8 + h) * NINP;
            float w0 = attp[(h * 6 + 0) * 6 + kk];
            float w1 = attp[(h * 6 + 1) * 6 + kk];
            float w2 = attp[(h * 6 + 2) * 6 + kk];
            float w3 = attp[(h * 6 + 3) * 6 + kk];
            float w4 = attp[(h * 6 + 4) * 6 + kk];
            float w5 = attp[(h * 6 + 5) * 6 + kk];
            float v[5];
            #pragma unroll
            for (int i = 0; i < 5; i++) {
                int c = tid + (i << 9);
                v[i] = (c < NINP) ? vb[c] : 0.f;
            }
            #pragma unroll
            for (int i = 0; i < 5; i++) {
                fa0[i] += w0 * v[i]; fa1[i] += w1 * v[i]; fa2[i] += w2 * v[i];
                fa3[i] += w3 * v[i]; fa4[i] += w4 * v[i]; fa5[i] += w5 * v[i];
            }
        }
    }
    // LayerNorm per q-row over 2400
    {
        float s[6] = {}, s2[6] = {};
        #pragma unroll
        for (int i = 0; i < 5; i++) {
            s[0] += fa0[i]; s2[0] += fa0[i] * fa0[i];
            s[1] += fa1[i]; s2[1] += fa1[i] * fa1[i];
            s[2] += fa2[i]; s2[2] += fa2[i] * fa2[i];
            s[3] += fa3[i]; s2[3] += fa3[i] * fa3[i];
            s[4] += fa4[i]; s2[4] += fa4[i] * fa4[i];
            s[5] += fa5[i]; s2[5] += fa5[i] * fa5[i];
        }
        #pragma unroll
        for (int off = 32; off; off >>= 1) {
            #pragma unroll
            for (int q = 0; q < 6; q++) {
                s[q] += __shfl_down(s[q], off);
                s2[q] += __shfl_down(s2[q], off);
            }
        }
        int wid = tid >> 6, lane = tid & 63;
        if (lane == 0) {
            #pragma unroll
            for (int q = 0; q < 6; q++) { aw[wid][q] = s[q]; bw[wid][q] = s2[q]; }
        }
    }
    __syncthreads();
    if (tid < 6) {
        float a = 0, a2 = 0;
        #pragma unroll
        for (int w = 0; w < 8; w++) { a += aw[w][tid]; a2 += bw[w][tid]; }
        float mu = a / NINP;
        float var = a2 / NINP - mu * mu;
        mu_s[tid] = mu;
        rs_s[tid] = 1.0f / sqrtf(var + 1e-5f);
    }
    __syncthreads();
    {
        float mu0 = mu_s[0], r0 = rs_s[0], mu1 = mu_s[1], r1 = rs_s[1];
        float mu2 = mu_s[2], r2 = rs_s[2], mu3 = mu_s[3], r3 = rs_s[3];
        float mu4 = mu_s[4], r4 = rs_s[4], mu5 = mu_s[5], r5 = rs_s[5];
        #pragma unroll
        for (int i = 0; i < 5; i++) {
            int c = tid + (i << 9);
            if (c < NINP) {
                float g = lg[c], be = lbta[c];
                long rb = (long)(b * 6) * NINP + c;
                inp[rb]             = (fa0[i] - mu0) * r0 * g + be;
                inp[rb + NINP]      = (fa1[i] - mu1) * r1 * g + be;
                inp[rb + 2 * NINP]  = (fa2[i] - mu2) * r2 * g + be;
                inp[rb + 3 * NINP]  = (fa3[i] - mu3) * r3 * g + be;
                inp[rb + 4 * NINP]  = (fa4[i] - mu4) * r4 * g + be;
                inp[rb + 5 * NINP]  = (fa5[i] - mu5) * r5 * g + be;
            }
        }
    }
}

// ---------------------------------------------------------------------------
// Fallback phase-B stage 1 (round-3): att_small + Gram scores + PV -> attV.
// grid = 256 (b*8+h).
// ---------------------------------------------------------------------------
template <bool FIRST>
__global__ __launch_bounds__(256) void fusedatt_fb_kernel(
    const float* __restrict__ htmp, const float* __restrict__ h0l1,
    float* __restrict__ out1_prev,
    const float* __restrict__ KMt, const float* __restrict__ VHt,
    float* __restrict__ attV,
    const float* __restrict__ mq, const float* __restrict__ mk,
    const float* __restrict__ mv, const float* __restrict__ mfc,
    const float* __restrict__ mg, const float* __restrict__ mb)
{
    __shared__ __align__(16) float hb[1200];
    __shared__ __align__(16) float aux[2896];
    __shared__ float attp[72];
    __shared__ float attr[36];
    const int blk = blockIdx.x, b = blk >> 3, h = blk & 7, tid = threadIdx.x;
    if (FIRST) {
        for (int i = tid; i < 300; i += 256)
            ((float4*)hb)[i] = ((const float4*)(h0l1 + b * NHID))[i];
        __syncthreads();
    } else {
        for (int i = tid; i < 300; i += 256)
            ((float4*)hb)[i] = ((const float4*)(htmp + b * NHID))[i];
        __syncthreads();
        att_inline<256>(hb, aux, (h == 0) ? out1_prev + b * NHID : nullptr,
                        mq, mk, mv, mfc, mg, mb);
    }
    const float* kb = KMt + (long)b * 9600 + h * 200;
    if (tid < 72) {
        int r = tid >> 1, half = tid & 1;
        int q = r / 6, kk = r % 6;
        const float4* qr = (const float4*)(hb + q * 200 + half * 100);
        const float4* kr = (const float4*)(kb + (long)kk * L1D + half * 100);
        float s0 = 0, s1 = 0, s2 = 0, s3 = 0;
        #pragma unroll 5
        for (int d = 0; d < 25; d++) {
            float4 a = qr[d], v = kr[d];
            s0 += a.x * v.x; s1 += a.y * v.y; s2 += a.z * v.z; s3 += a.w * v.w;
        }
        attp[tid] = s0 + s1 + s2 + s3;
    }
    __syncthreads();
    if (tid < 6) {
        float v[6]; float mx = -1e30f;
        #pragma unroll
        for (int kk = 0; kk < 6; kk++) {
            float s = (attp[(tid * 6 + kk) * 2] + attp[(tid * 6 + kk) * 2 + 1]) * 0.07071067811865475f;
            v[kk] = s; mx = fmaxf(mx, s);
        }
        float sm = 0;
        #pragma unroll
        for (int kk = 0; kk < 6; kk++) { v[kk] = expf(v[kk] - mx); sm += v[kk]; }
        float inv = 1.f / sm;
        #pragma unroll
        for (int kk = 0; kk < 6; kk++) attr[tid * 6 + kk] = v[kk] * inv;
    }
    __syncthreads();
    if (tid < 200) {
        int hd = h * 200 + tid;
        const float* vb = VHt + (long)b * 9600 + hd;
        float v0 = vb[0], v1 = vb[L1D], v2 = vb[2 * L1D];
        float v3 = vb[3 * L1D], v4 = vb[4 * L1D], v5 = vb[5 * L1D];
        #pragma unroll
        for (int q = 0; q < 6; q++) {
            const float* a = attr + q * 6;
            attV[(long)b * 9600 + q * L1D + hd] =
                a[0] * v0 + a[1] * v1 + a[2] * v2 + a[3] * v3 + a[4] * v4 + a[5] * v5;
        }
    }
}

// ---------------------------------------------------------------------------
// Standalone att_small (final out1[31]). grid = 32 (b).
// ---------------------------------------------------------------------------
__global__ __launch_bounds__(256) void attsmall_kernel(
    const float* __restrict__ h_in, float* __restrict__ h_out,
    const float* __restrict__ mq, const float* __restrict__ mk,
    const float* __restrict__ mv, const float* __restrict__ mfc,
    const float* __restrict__ mg, const float* __restrict__ mb)
{
    __shared__ __align__(16) float hb[1200];
    __shared__ __align__(16) float aux[2896];
    const int b = blockIdx.x, tid = threadIdx.x;
    for (int i = tid; i < 300; i += 256)
        ((float4*)hb)[i] = ((const float4*)(h_in + b * NHID))[i];
    __syncthreads();
    att_inline<256>(hb, aux, h_out + b * NHID, mq, mk, mv, mfc, mg, mb);
}

// ---------------------------------------------------------------------------
// Sum 8 split-K partials + LayerNorm over 2400 (fallback). grid = 192.
// ---------------------------------------------------------------------------
__global__ __launch_bounds__(256) void ln_sum8_kernel(
    const float* __restrict__ Fp, float* __restrict__ Y,
    const float* __restrict__ g, const float* __restrict__ bta)
{
    __shared__ float rowbuf[2400];
    __shared__ float aw[4], bw[4];
    const int r = blockIdx.x, tid = threadIdx.x;
    const long SL = (long)192 * NINP / 4;
    const float4* f0 = (const float4*)(Fp) + (long)r * (NINP / 4);
    float s = 0, s2 = 0;
    for (int i = tid; i < 600; i += 256) {
        float4 v = f0[i];
        #pragma unroll
        for (int z = 1; z < 8; z++) {
            float4 a = f0[(long)z * SL + i];
            v.x += a.x; v.y += a.y; v.z += a.z; v.w += a.w;
        }
        ((float4*)rowbuf)[i] = v;
        s += v.x + v.y + v.z + v.w;
        s2 += v.x * v.x + v.y * v.y + v.z * v.z + v.w * v.w;
    }
    for (int off = 32; off; off >>= 1) { s += __shfl_down(s, off); s2 += __shfl_down(s2, off); }
    int wid = tid >> 6, lane = tid & 63;
    if (lane == 0) { aw[wid] = s; bw[wid] = s2; }
    __syncthreads();
    if (tid == 0) {
        float a = 0, a2 = 0;
        for (int w = 0; w < 4; w++) { a += aw[w]; a2 += bw[w]; }
        float mu = a / NINP;
        float var = a2 / NINP - mu * mu;
        aw[0] = mu;
        bw[0] = 1.0f / sqrtf(var + 1e-5f);
    }
    __syncthreads();
    float mu = aw[0], rstd = bw[0];
    for (int i = tid; i < 600; i += 256) {
        float4 v = ((float4*)rowbuf)[i];
        float4 g4 = ((const float4*)g)[i];
        float4 b4 = ((const float4*)bta)[i];
        float4 o;
        o.x = (v.x - mu) * rstd * g4.x + b4.x;
        o.y = (v.y - mu) * rstd * g4.y + b4.y;
        o.z = (v.z - mu) * rstd * g4.z + b4.z;
        o.w = (v.w - mu) * rstd * g4.w + b4.w;
        ((float4*)(Y + (long)r * NINP))[i] = o;
    }
}

// ---------------------------------------------------------------------------
// Layer-1 LSTM step: gates = inp@Wi^T + h@Wh^T + bih + bhh. grid (50,6) x 512.
// ---------------------------------------------------------------------------
__global__ __launch_bounds__(512) void lstm1_kernel(
    const float* __restrict__ inp, const float* __restrict__ hprev,
    float* __restrict__ c_io, const float* __restrict__ Wi,
    const float* __restrict__ Wh, const float* __restrict__ bih,
    const float* __restrict__ bhh, float* __restrict__ h_out)
{
    __shared__ float h_s[200 * 33];
    __shared__ float x_s[2][100 * 33];
    __shared__ float ps[12][128];
    const int k = blockIdx.y, jt = blockIdx.x, tid = threadIdx.x;
    const int b = tid & 31, jg = (tid >> 5) & 3, kh = tid >> 7;
    const int j = jt * 4 + jg;

    for (int idx = tid; idx < 1600; idx += 512) {
        int bb = idx / 50, m4 = idx % 50;
        float4 v = *(const float4*)&hprev[bb * NHID + k * BS + m4 * 4];
        h_s[(m4 * 4 + 0) * 33 + bb] = v.x;
        h_s[(m4 * 4 + 1) * 33 + bb] = v.y;
        h_s[(m4 * 4 + 2) * 33 + bb] = v.z;
        h_s[(m4 * 4 + 3) * 33 + bb] = v.w;
    }
    for (int idx = tid; idx < 800; idx += 512) {
        int bb = idx / 25, m4 = idx % 25;
        float4 v = *(const float4*)&inp[(long)(bb * 6 + k) * NINP + m4 * 4];
        x_s[0][(m4 * 4 + 0) * 33 + bb] = v.x;
        x_s[0][(m4 * 4 + 1) * 33 + bb] = v.y;
        x_s[0][(m4 * 4 + 2) * 33 + bb] = v.z;
        x_s[0][(m4 * 4 + 3) * 33 + bb] = v.w;
    }

    const float* wi0 = Wi + (long)(k * 800 + j) * NINP;
    const float* wi1 = wi0 + (long)200 * NINP;
    const float* wi2 = wi0 + (long)400 * NINP;
    const float* wi3 = wi0 + (long)600 * NINP;
    float a0 = 0, a1 = 0, a2 = 0, a3 = 0;
    int cur = 0;
    for (int ti = 0; ti < 24; ti++) {
        __syncthreads();
        if (ti + 1 < 24) {
            int kt = (ti + 1) * 100;
            float* xs = x_s[cur ^ 1];
            for (int idx = tid; idx < 800; idx += 512) {
                int bb = idx / 25, m4 = idx % 25;
                float4 v = *(const float4*)&inp[(long)(bb * 6 + k) * NINP + kt + m4 * 4];
                xs[(m4 * 4 + 0) * 33 + bb] = v.x;
                xs[(m4 * 4 + 1) * 33 + bb] = v.y;
                xs[(m4 * 4 + 2) * 33 + bb] = v.z;
                xs[(m4 * 4 + 3) * 33 + bb] = v.w;
            }
        }
        if (ti / 6 == kh) {
            const int kt = ti * 100;
            const float* xs = x_s[cur];
            for (int m = 0; m < 100; m += 4) {
                float4 w0 = *(const float4*)&wi0[kt + m];
                float4 w1 = *(const float4*)&wi1[kt + m];
                float4 w2 = *(const float4*)&wi2[kt + m];
                float4 w3 = *(const float4*)&wi3[kt + m];
                float x0 = xs[(m + 0) * 33 + b], x1 = xs[(m + 1) * 33 + b];
                float x2 = xs[(m + 2) * 33 + b], x3 = xs[(m + 3) * 33 + b];
                a0 += x0 * w0.x + x1 * w0.y + x2 * w0.z + x3 * w0.w;
                a1 += x0 * w1.x + x1 * w1.y + x2 * w1.z + x3 * w1.w;
                a2 += x0 * w2.x + x1 * w2.y + x2 * w2.z + x3 * w2.w;
                a3 += x0 * w3.x + x1 * w3.y + x2 * w3.z + x3 * w3.w;
            }
        }
        cur ^= 1;
    }
    if (kh == 0) {
        const float* w0 = Wh + (long)(k * 800 + j) * 200;
        const float* w1 = w0 + 200 * 200;
        const float* w2 = w0 + 400 * 200;
        const float* w3 = w0 + 600 * 200;
        for (int m = 0; m < 200; m += 4) {
            float4 wv0 = *(const float4*)&w0[m];
            float4 wv1 = *(const float4*)&w1[m];
            float4 wv2 = *(const float4*)&w2[m];
            float4 wv3 = *(const float4*)&w3[m];
            float h0v = h_s[(m + 0) * 33 + b], h1v = h_s[(m + 1) * 33 + b];
            float h2v = h_s[(m + 2) * 33 + b], h3v = h_s[(m + 3) * 33 + b];
            a0 += h0v * wv0.x + h1v * wv0.y + h2v * wv0.z + h3v * wv0.w;
            a1 += h0v * wv1.x + h1v * wv1.y + h2v * wv1.z + h3v * wv1.w;
            a2 += h0v * wv2.x + h1v * wv2.y + h2v * wv2.z + h3v * wv2.w;
            a3 += h0v * wv3.x + h1v * wv3.y + h2v * wv3.z + h3v * wv3.w;
        }
    } else {
        int g = (kh - 1) * 4, t2 = tid & 127;
        ps[g + 0][t2] = a0; ps[g + 1][t2] = a1; ps[g + 2][t2] = a2; ps[g + 3][t2] = a3;
    }
    __syncthreads();
    if (kh == 0) {
        a0 += ps[0][tid] + ps[4][tid] + ps[8][tid];
        a1 += ps[1][tid] + ps[5][tid] + ps[9][tid];
        a2 += ps[2][tid] + ps[6][tid] + ps[10][tid];
        a3 += ps[3][tid] + ps[7][tid] + ps[11][tid];
        int nb2 = k * 800;
        float gi = a0 + bih[nb2 + j] + bhh[nb2 + j];
        float gf = a1 + bih[nb2 + 200 + j] + bhh[nb2 + 200 + j];
        float gg = a2 + bih[nb2 + 400 + j] + bhh[nb2 + 400 + j];
        float go = a3 + bih[nb2 + 600 + j] + bhh[nb2 + 600 + j];
        int o = b * NHID + k * BS + j;
        float cold = c_io[o];
        float cn = sigmoidf_(gf) * cold + sigmoidf_(gi) * tanhf(gg);
        float hn = sigmoidf_(go) * tanhf(cn);
        c_io[o] = cn;
        h_out[o] = hn;
    }
}

// ---------------------------------------------------------------------------
extern "C" void kernel_launch(void* const* d_in, const int* in_sizes, int n_in,
                              void* d_out, int out_size, void* d_ws, size_t ws_size,
                              hipStream_t stream)
{
    const int*   tokens = (const int*)  d_in[0];
    const float* h0     = (const float*)d_in[1];
    const float* c0     = (const float*)d_in[2];
    const float* emb    = (const float*)d_in[3];
    const float* Wi     = (const float*)d_in[4];
    const float* Wh     = (const float*)d_in[5];
    const float* bih    = (const float*)d_in[6];
    const float* bhh    = (const float*)d_in[7];
    const float* mq     = (const float*)d_in[8];
    const float* mk     = (const float*)d_in[9];
    const float* mv     = (const float*)d_in[10];
    const float* mfc    = (const float*)d_in[11];
    const float* mg     = (const float*)d_in[12];
    const float* mb     = (const float*)d_in[13];
    const float* lq     = (const float*)d_in[14];
    const float* lk     = (const float*)d_in[15];
    const float* lv     = (const float*)d_in[16];
    const float* lfc    = (const float*)d_in[17];
    const float* lg     = (const float*)d_in[18];
    const float* lb     = (const float*)d_in[19];
    const float* dec_w  = (const float*)d_in[20];
    const float* dec_b  = (const float*)d_in[21];
    float* out = (float*)d_out;

    // workspace carve-up (floats) — common part
    float* p = (float*)d_ws;
    float* GX0  = p; p += (long)ROWS * NG;        // 4,915,200
    float* out0 = p; p += (long)ROWS * NHID;      // 1,228,800
    float* out1 = p; p += (long)ROWS * NHID;      // 1,228,800
    float* KM   = p; p += (long)ROWS * 6 * L1D;   // 9,830,400
    float* inp  = p; p += 192 * NINP;             // 460,800
    float* htmp = p; p += BZ * NHID;
    float* cb1  = p; p += BZ * NHID;
    float* BigB = p; p += 200 * L1D;
    float* WhT  = p; p += 6 * 200 * 800;
    long common = p - (float*)d_ws;
    const long LVF_SZ  = (long)8 * 200 * NINP;             // 3,840,000 (15.4 MB)
    const long CHB_SZ  = (long)CH * BZ * 6 * 8 * NINP;     // 7,372,800 (29.5 MB)
    const bool use_vfh =
        ws_size >= (size_t)(common + LVF_SZ + CHB_SZ + 1024) * sizeof(float); // ~121 MB

    long off = (long)ROWS * NTOK;
    float* cf0 = out + off + 2 * ST;

    hipMemcpyAsync(cb1, c0 + ST, ST * sizeof(float), hipMemcpyDeviceToDevice, stream);

    bigb_kernel<<<1250, 256, 0, stream>>>(lq, lk, BigB);
    whT_kernel<<<3750, 256, 0, stream>>>(Wh, WhT);

    // GX0 = emb[tokens] @ Wi^T + bih + bhh
    gemm128_kernel<true><<<dim3(NG / 128 + 1, ROWS / 128), 256, 0, stream>>>(
        emb, Wi, bih, bhh, GX0, ROWS, NG, NINP, tokens);

    // Phase A
    phaseA_kernel<<<BZ, 1024, 0, stream>>>(
        GX0, h0, c0, WhT, out0, cf0, mq, mk, mv, mfc, mg, mb);

    // KM = out0 @ BigB (Gram-projected keys)
    gemm128_kernel<false><<<dim3((L1D + 127) / 128, (ROWS * 6) / 128), 256, 0, stream>>>(
        out0, BigB, nullptr, nullptr, KM, ROWS * 6, L1D, BS, nullptr);

    if (use_vfh) {
        float* LVF  = p;
        float* VFhC = p + LVF_SZ;   // chunk buffer: CH timesteps of VFh rows
        // LVF[h] = lv_h (200x200 over m) @ lfc_h (200x2400)
        gemmz_kernel<<<dim3((NINP + 127) / 128, 2, 8), 256, 0, stream>>>(
            lv, lfc, LVF, 200, NINP, 200,
            (long)L1D, 200L, (long)200 * NINP, (long)NINP, (long)200 * NINP);

        const int MCH = CH * BZ * 6;                  // rows per chunk (384)
        for (int c = 0; c < TT / CH; c++) {
            // VFhC[(tt,b,kk), h, c] = out0-chunk (384x200) @ LVF[h]
            gemmz_kernel<<<dim3((NINP + 127) / 128, MCH / 128, 8), 256, 0, stream>>>(
                out0 + (long)c * MCH * 200, LVF, VFhC, MCH, NINP, 200,
                200L, 0L, (long)200 * NINP, (long)8 * NINP, (long)NINP);
            for (int tt = 0; tt < CH; tt++) {
                int t = c * CH + tt;
                const float* hp = (t == 0) ? h0 + ST : out1 + (long)(t - 1) * ST;
                const float* KMt = KM + (long)t * BZ * 6 * L1D;
                const float* VFht = VFhC + (long)tt * BZ * 6 * 8 * NINP;
                if (t == 0) {
                    fusedatt_vfh_kernel<true><<<BZ, 512, 0, stream>>>(
                        h0 + ST, nullptr, KMt, VFht, inp, lg, lb,
                        mq, mk, mv, mfc, mg, mb);
                } else {
                    fusedatt_vfh_kernel<false><<<BZ, 512, 0, stream>>>(
                        htmp, out1 + (long)(t - 1) * ST, KMt, VFht, inp, lg, lb,
                        mq, mk, mv, mfc, mg, mb);
                }
                lstm1_kernel<<<dim3(50, 6), 512, 0, stream>>>(
                    inp, hp, cb1, Wi, Wh, bih, bhh, htmp);
            }
        }
    } else {
        // fallback: round-3 proven 4-launch pipeline
        float* VH1  = p;
        float* attV = VH1 + (long)ROWS * 6 * L1D;
        float* FCp  = attV + 192 * L1D;
        gemm128_kernel<false><<<dim3((L1D + 127) / 128, (ROWS * 6) / 128), 256, 0, stream>>>(
            out0, lv, nullptr, nullptr, VH1, ROWS * 6, L1D, BS, nullptr);
        for (int t = 0; t < TT; t++) {
            const float* hp = (t == 0) ? h0 + ST : out1 + (long)(t - 1) * ST;
            const float* KMt = KM + (long)t * BZ * 6 * L1D;
            const float* VHt = VH1 + (long)t * BZ * 6 * L1D;
            if (t == 0) {
                fusedatt_fb_kernel<true><<<256, 256, 0, stream>>>(
                    nullptr, h0 + ST, nullptr, KMt, VHt, attV, mq, mk, mv, mfc, mg, mb);
            } else {
                fusedatt_fb_kernel<false><<<256, 256, 0, stream>>>(
                    htmp, nullptr, out1 + (long)(t - 1) * ST, KMt, VHt, attV,
                    mq, mk, mv, mfc, mg, mb);
            }
            gemm_skp_kernel<<<dim3((NINP + 63) / 64, 3, 8), 256, 0, stream>>>(
                attV, lfc, FCp, 192, NINP, L1D, 200);
            ln_sum8_kernel<<<192, 256, 0, stream>>>(FCp, inp, lg, lb);
            lstm1_kernel<<<dim3(50, 6), 512, 0, stream>>>(
                inp, hp, cb1, Wi, Wh, bih, bhh, htmp);
        }
    }

    attsmall_kernel<<<BZ, 256, 0, stream>>>(htmp, out1 + (long)31 * ST, mq, mk, mv, mfc, mg, mb);

    // decode
    gemm128_kernel<true><<<dim3(NTOK / 128, ROWS / 128), 256, 0, stream>>>(
        out1, dec_w, dec_b, nullptr, out, ROWS, NTOK, NHID, nullptr);

    hipMemcpyAsync(out + off,          out0 + (long)31 * ST, ST * sizeof(float), hipMemcpyDeviceToDevice, stream);
    hipMemcpyAsync(out + off + ST,     out1 + (long)31 * ST, ST * sizeof(float), hipMemcpyDeviceToDevice, stream);
    hipMemcpyAsync(out + off + 3 * ST, cb1,                  ST * sizeof(float), hipMemcpyDeviceToDevice, stream);
}

// Round 8
// 10211.168 us; speedup vs baseline: 1.2298x; 1.0679x over previous
//
#include <hip/hip_runtime.h>
#include <math.h>

// Model dims
#define NBLK 6
#define BS   200
#define NHID 1200
#define NINP 2400
#define TT   32
#define BZ   32
#define NTOK 16000
#define NG   4800      // NBLK*4*BS
#define ROWS 1024      // TT*BZ
#define L1D  1600      // 8 heads * 200
#define ST   (BZ*NHID) // 38400 floats per (32,1200) state; == 192*200

__device__ __forceinline__ float sigmoidf_(float x) { return 1.0f / (1.0f + expf(-x)); }

// ---------------------------------------------------------------------------
// 128x128-tile fp32 GEMM, 8x8 per thread. C[M,N] = A[M,K] @ B (+bias1+bias2)
// BT=false: B is (K,N) row-major. BT=true: B is (N,K) row-major.
// a_idx: optional row gather. Requires M % 128 == 0, K % 8 == 0, N % 4 == 0.
// ---------------------------------------------------------------------------
template <bool BT>
__global__ __launch_bounds__(256) void gemm128_kernel(
    const float* __restrict__ A, const float* __restrict__ B,
    const float* __restrict__ bias1, const float* __restrict__ bias2,
    float* __restrict__ C, int M, int N, int K, const int* __restrict__ a_idx)
{
    __shared__ __align__(16) float As[8][132];
    __shared__ __align__(16) float Bs[8][132];
    const int tid = threadIdx.x;
    const int tx = tid & 15, ty = tid >> 4;
    const int n0 = blockIdx.x * 128, m0 = blockIdx.y * 128;

    const int la_r = tid >> 1, la_k = (tid & 1) * 4;
    long arow;
    {
        int row = m0 + la_r;
        arow = a_idx ? (long)a_idx[row] * K : (long)row * K;
    }
    float acc[8][8] = {};

    for (int k0 = 0; k0 < K; k0 += 8) {
        {
            float4 v = *(const float4*)&A[arow + k0 + la_k];
            As[la_k + 0][la_r] = v.x;
            As[la_k + 1][la_r] = v.y;
            As[la_k + 2][la_r] = v.z;
            As[la_k + 3][la_r] = v.w;
        }
        if constexpr (!BT) {
            int kk = tid >> 5, n = (tid & 31) * 4;
            int col = n0 + n;
            float4 v = make_float4(0.f, 0.f, 0.f, 0.f);
            if (col < N) v = *(const float4*)&B[(long)(k0 + kk) * N + col];
            *(float4*)&Bs[kk][n] = v;
        } else {
            int n = tid >> 1, kk0 = (tid & 1) * 4;
            int col = n0 + n;
            float4 v = make_float4(0.f, 0.f, 0.f, 0.f);
            if (col < N) v = *(const float4*)&B[(long)col * K + k0 + kk0];
            Bs[kk0 + 0][n] = v.x;
            Bs[kk0 + 1][n] = v.y;
            Bs[kk0 + 2][n] = v.z;
            Bs[kk0 + 3][n] = v.w;
        }
        __syncthreads();
        #pragma unroll
        for (int kk = 0; kk < 8; kk++) {
            float av[8], bv[8];
            *(float4*)&av[0] = *(const float4*)&As[kk][ty * 4];
            *(float4*)&av[4] = *(const float4*)&As[kk][ty * 4 + 64];
            *(float4*)&bv[0] = *(const float4*)&Bs[kk][tx * 4];
            *(float4*)&bv[4] = *(const float4*)&Bs[kk][tx * 4 + 64];
            #pragma unroll
            for (int i = 0; i < 8; i++)
                #pragma unroll
                for (int j = 0; j < 8; j++) acc[i][j] += av[i] * bv[j];
        }
        __syncthreads();
    }
    #pragma unroll
    for (int i = 0; i < 8; i++) {
        int row = m0 + ty * 4 + (i & 3) + (i >> 2) * 64;
        #pragma unroll
        for (int jg = 0; jg < 2; jg++) {
            int col = n0 + tx * 4 + jg * 64;
            if (col < N) {
                float4 v;
                v.x = acc[i][jg * 4 + 0]; v.y = acc[i][jg * 4 + 1];
                v.z = acc[i][jg * 4 + 2]; v.w = acc[i][jg * 4 + 3];
                if (bias1) {
                    float4 b1 = *(const float4*)&bias1[col];
                    v.x += b1.x; v.y += b1.y; v.z += b1.z; v.w += b1.w;
                }
                if (bias2) {
                    float4 b2 = *(const float4*)&bias2[col];
                    v.x += b2.x; v.y += b2.y; v.z += b2.z; v.w += b2.w;
                }
                *(float4*)&C[(long)row * N + col] = v;
            }
        }
    }
}

// ---------------------------------------------------------------------------
// Batched (z) 128x128 GEMM with strides (used for LVF and VFh bootstrap).
// ---------------------------------------------------------------------------
__global__ __launch_bounds__(256) void gemmz_kernel(
    const float* __restrict__ A, const float* __restrict__ B, float* __restrict__ C,
    int M, int N, int K,
    long a_rstride, long a_zoff, long b_zoff, long c_rstride, long c_zoff)
{
    __shared__ __align__(16) float As[8][132];
    __shared__ __align__(16) float Bs[8][132];
    const int tid = threadIdx.x;
    const int tx = tid & 15, ty = tid >> 4;
    const int n0 = blockIdx.x * 128, m0 = blockIdx.y * 128;
    const int z = blockIdx.z;
    const float* Az = A + a_zoff * z;
    const float* Bz = B + b_zoff * z;
    float* Cz = C + c_zoff * z;

    const int la_r = tid >> 1, la_k = (tid & 1) * 4;
    int arow_i = m0 + la_r; if (arow_i >= M) arow_i = M - 1;
    const long arow = (long)arow_i * a_rstride;
    float acc[8][8] = {};

    for (int k0 = 0; k0 < K; k0 += 8) {
        {
            float4 v = *(const float4*)&Az[arow + k0 + la_k];
            As[la_k + 0][la_r] = v.x;
            As[la_k + 1][la_r] = v.y;
            As[la_k + 2][la_r] = v.z;
            As[la_k + 3][la_r] = v.w;
        }
        {
            int kk = tid >> 5, n = (tid & 31) * 4;
            int col = n0 + n;
            float4 v = make_float4(0.f, 0.f, 0.f, 0.f);
            if (col < N) v = *(const float4*)&Bz[(long)(k0 + kk) * N + col];
            *(float4*)&Bs[kk][n] = v;
        }
        __syncthreads();
        #pragma unroll
        for (int kk = 0; kk < 8; kk++) {
            float av[8], bv[8];
            *(float4*)&av[0] = *(const float4*)&As[kk][ty * 4];
            *(float4*)&av[4] = *(const float4*)&As[kk][ty * 4 + 64];
            *(float4*)&bv[0] = *(const float4*)&Bs[kk][tx * 4];
            *(float4*)&bv[4] = *(const float4*)&Bs[kk][tx * 4 + 64];
            #pragma unroll
            for (int i = 0; i < 8; i++)
                #pragma unroll
                for (int j = 0; j < 8; j++) acc[i][j] += av[i] * bv[j];
        }
        __syncthreads();
    }
    #pragma unroll
    for (int i = 0; i < 8; i++) {
        int row = m0 + ty * 4 + (i & 3) + (i >> 2) * 64;
        if (row >= M) continue;
        #pragma unroll
        for (int jg = 0; jg < 2; jg++) {
            int col = n0 + tx * 4 + jg * 64;
            if (col < N) {
                float4 v;
                v.x = acc[i][jg * 4 + 0]; v.y = acc[i][jg * 4 + 1];
                v.z = acc[i][jg * 4 + 2]; v.w = acc[i][jg * 4 + 3];
                *(float4*)&Cz[(long)row * c_rstride + col] = v;
            }
        }
    }
}

// ---------------------------------------------------------------------------
// Piggyback GEMM tile: C(rowstride 8*NINP) += chunk of out0_next(192x200) @ B.
// One 128x128 tile (mt,nt) of head z. Runs inside fusedattF/lstm1ln launches.
// 'act' = thread participates (first 256 threads); all threads hit the syncs.
// ---------------------------------------------------------------------------
__device__ __forceinline__ void piggy_tile(
    float* smem, int tid, bool act,
    const float* __restrict__ A,   // 192 x 200
    const float* __restrict__ B,   // 200 x NINP (head slice of LVF)
    float* __restrict__ C,         // head-offset applied; row stride 8*NINP
    int mt, int nt)
{
    float* As = smem;          // [8][132]
    float* Bs = smem + 1056;   // [8][132]
    const int tx = tid & 15, ty = (tid >> 4) & 15;
    const int n0 = nt * 128, m0 = mt * 128;
    const int la_r = (tid & 255) >> 1, la_k = (tid & 1) * 4;
    int arow_i = m0 + la_r; if (arow_i > 191) arow_i = 191;
    float acc[8][8] = {};
    for (int k0 = 0; k0 < 200; k0 += 8) {
        if (act) {
            float4 v = *(const float4*)&A[(long)arow_i * 200 + k0 + la_k];
            As[(la_k + 0) * 132 + la_r] = v.x;
            As[(la_k + 1) * 132 + la_r] = v.y;
            As[(la_k + 2) * 132 + la_r] = v.z;
            As[(la_k + 3) * 132 + la_r] = v.w;
            int kk = (tid >> 5) & 7, n = (tid & 31) * 4;
            int col = n0 + n;
            float4 w = make_float4(0.f, 0.f, 0.f, 0.f);
            if (col < NINP) w = *(const float4*)&B[(long)(k0 + kk) * NINP + col];
            *(float4*)&Bs[kk * 132 + n] = w;
        }
        __syncthreads();
        if (act) {
            #pragma unroll
            for (int kk = 0; kk < 8; kk++) {
                float av[8], bv[8];
                *(float4*)&av[0] = *(const float4*)&As[kk * 132 + ty * 4];
                *(float4*)&av[4] = *(const float4*)&As[kk * 132 + ty * 4 + 64];
                *(float4*)&bv[0] = *(const float4*)&Bs[kk * 132 + tx * 4];
                *(float4*)&bv[4] = *(const float4*)&Bs[kk * 132 + tx * 4 + 64];
                #pragma unroll
                for (int i = 0; i < 8; i++)
                    #pragma unroll
                    for (int j = 0; j < 8; j++) acc[i][j] += av[i] * bv[j];
            }
        }
        __syncthreads();
    }
    if (act) {
        #pragma unroll
        for (int i = 0; i < 8; i++) {
            int row = m0 + ty * 4 + (i & 3) + (i >> 2) * 64;
            if (row >= 192) continue;
            #pragma unroll
            for (int jg = 0; jg < 2; jg++) {
                int col = n0 + tx * 4 + jg * 64;
                if (col < NINP) {
                    float4 v;
                    v.x = acc[i][jg * 4 + 0]; v.y = acc[i][jg * 4 + 1];
                    v.z = acc[i][jg * 4 + 2]; v.w = acc[i][jg * 4 + 3];
                    *(float4*)&C[(long)row * (8L * NINP) + col] = v;
                }
            }
        }
    }
}

// ---------------------------------------------------------------------------
// BigB[c'][h*200+c] = sum_d lq[c, h*200+d] * lk[c', h*200+d]   (200 x 1600)
// ---------------------------------------------------------------------------
__global__ __launch_bounds__(256) void bigb_kernel(
    const float* __restrict__ lq, const float* __restrict__ lk,
    float* __restrict__ BigB)
{
    int id = blockIdx.x * 256 + threadIdx.x;
    if (id >= 320000) return;
    int h = id / 40000, r = id % 40000, cp = r / 200, c = r % 200;
    const float4* a = (const float4*)(lq + (long)c * L1D + h * 200);
    const float4* b = (const float4*)(lk + (long)cp * L1D + h * 200);
    float s0 = 0, s1 = 0, s2 = 0, s3 = 0;
    #pragma unroll 5
    for (int d = 0; d < 50; d++) {
        float4 av = a[d], bv = b[d];
        s0 += av.x * bv.x; s1 += av.y * bv.y; s2 += av.z * bv.z; s3 += av.w * bv.w;
    }
    BigB[(long)cp * L1D + h * 200 + c] = s0 + s1 + s2 + s3;
}

// ---------------------------------------------------------------------------
// WhT[(k*200+m)*800 + g] = Wh[(k*800+g)*200 + m]
// ---------------------------------------------------------------------------
__global__ __launch_bounds__(256) void whT_kernel(
    const float* __restrict__ Wh, float* __restrict__ WhT)
{
    int id = blockIdx.x * 256 + threadIdx.x;
    if (id >= 960000) return;
    int k = id / 160000, r = id % 160000, m = r / 800, g = r % 800;
    WhT[id] = Wh[(long)(k * 800 + g) * 200 + m];
}

// ---------------------------------------------------------------------------
// Small self-attention (nh=4, dk=dv=16) + residual + LN over 200, in-LDS.
// ---------------------------------------------------------------------------
template <int NT>
__device__ __forceinline__ void att_inline(
    float* hb, float* aux, float* gout,
    const float* __restrict__ mq, const float* __restrict__ mk,
    const float* __restrict__ mv, const float* __restrict__ mfc,
    const float* __restrict__ mg, const float* __restrict__ mb)
{
    const int tid = threadIdx.x;
    float* qh   = aux;          // 384
    float* kh   = aux + 384;    // 384
    float* vh   = aux + 768;    // 384
    float* att  = aux + 1152;   // 144
    float* outp = aux + 1296;   // 384
    float* o2   = aux + 1680;   // 1200
    float* mu_s = aux + 2880;   // 6
    float* rs_s = aux + 2888;   // 6
    if (tid < 192) {
        int which = tid >> 6, hd = tid & 63;
        const float* Mw = which == 0 ? mq : (which == 1 ? mk : mv);
        float acc[6] = {};
        for (int jx = 0; jx < 200; jx++) {
            float w = Mw[jx * 64 + hd];
            #pragma unroll
            for (int l = 0; l < 6; l++) acc[l] += hb[l * 200 + jx] * w;
        }
        float* dst = which == 0 ? qh : (which == 1 ? kh : vh);
        #pragma unroll
        for (int l = 0; l < 6; l++) dst[l * 64 + hd] = acc[l];
    }
    __syncthreads();
    if (tid < 144) {
        int h = tid / 36, r = tid % 36, q = r / 6, kk = r % 6;
        float s = 0;
        #pragma unroll
        for (int d = 0; d < 16; d++) s += qh[q * 64 + h * 16 + d] * kh[kk * 64 + h * 16 + d];
        att[(h * 6 + q) * 6 + kk] = s * 0.25f;
    }
    __syncthreads();
    if (tid < 24) {
        float* a = att + tid * 6;
        float mx = a[0];
        for (int i = 1; i < 6; i++) mx = fmaxf(mx, a[i]);
        float sm = 0;
        for (int i = 0; i < 6; i++) { a[i] = expf(a[i] - mx); sm += a[i]; }
        float inv = 1.f / sm;
        for (int i = 0; i < 6; i++) a[i] *= inv;
    }
    __syncthreads();
    for (int id = tid; id < 384; id += NT) {
        int q = id >> 6, hd = id & 63, h = hd >> 4;
        float s = 0;
        #pragma unroll
        for (int kk = 0; kk < 6; kk++) s += att[(h * 6 + q) * 6 + kk] * vh[kk * 64 + hd];
        outp[id] = s;
    }
    __syncthreads();
    if (tid < 200) {
        float acc[6] = {};
        for (int d = 0; d < 64; d++) {
            float w = mfc[d * 200 + tid];
            #pragma unroll
            for (int q = 0; q < 6; q++) acc[q] += outp[q * 64 + d] * w;
        }
        #pragma unroll
        for (int q = 0; q < 6; q++) o2[q * 200 + tid] = acc[q] + hb[q * 200 + tid];
    }
    __syncthreads();
    if (tid < 6) {
        const float4* o4 = (const float4*)(o2 + tid * 200);
        float s = 0, s2 = 0;
        for (int i = 0; i < 50; i++) {
            float4 v = o4[i];
            s += v.x + v.y + v.z + v.w;
            s2 += v.x * v.x + v.y * v.y + v.z * v.z + v.w * v.w;
        }
        float mu = s / 200.f;
        float var = s2 / 200.f - mu * mu;
        mu_s[tid] = mu;
        rs_s[tid] = 1.0f / sqrtf(var + 1e-5f);
    }
    __syncthreads();
    for (int i = tid; i < 300; i += NT) {
        int q = i / 50;
        float4 v = ((float4*)o2)[i];
        float4 g4 = ((const float4*)mg)[i % 50];
        float4 b4 = ((const float4*)mb)[i % 50];
        float mu = mu_s[q], rstd = rs_s[q];
        float4 r;
        r.x = (v.x - mu) * rstd * g4.x + b4.x;
        r.y = (v.y - mu) * rstd * g4.y + b4.y;
        r.z = (v.z - mu) * rstd * g4.z + b4.z;
        r.w = (v.w - mu) * rstd * g4.w + b4.w;
        ((float4*)hb)[i] = r;
        if (gout) ((float4*)(gout))[i] = r;
    }
    __syncthreads();
}

// ---------------------------------------------------------------------------
// Phase A: per-b scan, 32 blocks x 1024 thr. 5-chain MLP gate dots.
// ---------------------------------------------------------------------------
__global__ __launch_bounds__(1024) void phaseA_kernel(
    const float* __restrict__ GX0, const float* __restrict__ h0,
    const float* __restrict__ c0, const float* __restrict__ WhT,
    float* __restrict__ out0, float* __restrict__ cf0,
    const float* __restrict__ mq, const float* __restrict__ mk,
    const float* __restrict__ mv, const float* __restrict__ mfc,
    const float* __restrict__ mg, const float* __restrict__ mb)
{
    __shared__ __align__(16) float h_s[1200];
    __shared__ __align__(16) float c_s[1200];
    __shared__ __align__(16) float g_s[4800];
    __shared__ __align__(16) float aux_s[2896];
    const int b = blockIdx.x, tid = threadIdx.x;
    for (int i = tid; i < 300; i += 1024) {
        ((float4*)h_s)[i] = ((const float4*)(h0 + b * NHID))[i];
        ((float4*)c_s)[i] = ((const float4*)(c0 + b * NHID))[i];
    }
    __syncthreads();
    for (int t = 0; t < TT; t++) {
        // gates: h @ Wh^T, 1200 tasks (k,g-quad), 5 independent load chains
        for (int task = tid; task < 1200; task += 1024) {
            int k = task / 200, g = task - k * 200;
            const float* wp = WhT + (long)k * 160000 + g * 4;
            const float* hp2 = h_s + k * 200;
            float a0x = 0, a0y = 0, a0z = 0, a0w = 0;
            float a1x = 0, a1y = 0, a1z = 0, a1w = 0;
            float a2x = 0, a2y = 0, a2z = 0, a2w = 0;
            float a3x = 0, a3y = 0, a3z = 0, a3w = 0;
            float a4x = 0, a4y = 0, a4z = 0, a4w = 0;
            #pragma unroll 2
            for (int m = 0; m < 40; m++) {
                float h0v = hp2[m], h1v = hp2[m + 40], h2v = hp2[m + 80];
                float h3v = hp2[m + 120], h4v = hp2[m + 160];
                float4 w0 = *(const float4*)(wp + (long)m * 800);
                float4 w1 = *(const float4*)(wp + (long)(m + 40) * 800);
                float4 w2 = *(const float4*)(wp + (long)(m + 80) * 800);
                float4 w3 = *(const float4*)(wp + (long)(m + 120) * 800);
                float4 w4 = *(const float4*)(wp + (long)(m + 160) * 800);
                a0x += h0v * w0.x; a0y += h0v * w0.y; a0z += h0v * w0.z; a0w += h0v * w0.w;
                a1x += h1v * w1.x; a1y += h1v * w1.y; a1z += h1v * w1.z; a1w += h1v * w1.w;
                a2x += h2v * w2.x; a2y += h2v * w2.y; a2z += h2v * w2.z; a2w += h2v * w2.w;
                a3x += h3v * w3.x; a3y += h3v * w3.y; a3z += h3v * w3.z; a3w += h3v * w3.w;
                a4x += h4v * w4.x; a4y += h4v * w4.y; a4z += h4v * w4.z; a4w += h4v * w4.w;
            }
            int o = k * 800 + g * 4;
            g_s[o]     = a0x + a1x + a2x + a3x + a4x;
            g_s[o + 1] = a0y + a1y + a2y + a3y + a4y;
            g_s[o + 2] = a0z + a1z + a2z + a3z + a4z;
            g_s[o + 3] = a0w + a1w + a2w + a3w + a4w;
        }
        __syncthreads();
        const float* gxp = GX0 + ((long)t * BZ + b) * NG;
        for (int idx = tid; idx < 1200; idx += 1024) {
            int k = idx / 200, j = idx - k * 200;
            int base = k * 800 + j;
            float gi = g_s[base]       + gxp[base];
            float gf = g_s[base + 200] + gxp[base + 200];
            float gg = g_s[base + 400] + gxp[base + 400];
            float go = g_s[base + 600] + gxp[base + 600];
            float cn = sigmoidf_(gf) * c_s[idx] + sigmoidf_(gi) * tanhf(gg);
            c_s[idx] = cn;
            h_s[idx] = sigmoidf_(go) * tanhf(cn);
        }
        __syncthreads();
        att_inline<1024>(h_s, aux_s, out0 + (long)t * ST + b * NHID, mq, mk, mv, mfc, mg, mb);
    }
    for (int i = tid; i < 300; i += 1024)
        ((float4*)(cf0 + b * NHID))[i] = ((float4*)c_s)[i];
}

// ---------------------------------------------------------------------------
// fusedattF: blocks 0..255 = (b, c-slice): att_small(htmp)->out1[t-1] (cc==0),
// Gram scores + softmax (redundant per cc), F-slice = P * VFh, writes Fbuf +
// per-slice LN partials. Blocks >=256: piggyback VFh GEMM tiles (z 0..3, t+1).
// ---------------------------------------------------------------------------
template <bool FIRST>
__global__ __launch_bounds__(256) void fusedattF_kernel(
    const float* __restrict__ hraw, float* __restrict__ out1_prev,
    const float* __restrict__ KMt, const float* __restrict__ VFhc,
    float* __restrict__ Fbuf, float* __restrict__ pstat,
    const float* __restrict__ out0_next, const float* __restrict__ LVF,
    float* __restrict__ VFh_next,
    const float* __restrict__ mq, const float* __restrict__ mk,
    const float* __restrict__ mv, const float* __restrict__ mfc,
    const float* __restrict__ mg, const float* __restrict__ mb)
{
    __shared__ __align__(16) float smem[4608];
    const int blk = blockIdx.x, tid = threadIdx.x;
    if (blk >= 256) {
        int pid = blk - 256;
        int z = pid / 38, r = pid % 38, mt = r / 19, nt = r % 19;
        piggy_tile(smem, tid, true, out0_next, LVF + (long)z * 200 * NINP,
                   VFh_next + (long)z * NINP, mt, nt);
        return;
    }
    const int b = blk >> 3, cc = blk & 7;
    float* hb   = smem;            // 1200
    float* aux  = smem + 1200;     // 2896
    float* attp = smem + 4096;     // 288
    float* aw   = smem + 4384;     // 24
    float* bw   = smem + 4408;     // 24
    for (int i = tid; i < 300; i += 256)
        ((float4*)hb)[i] = ((const float4*)(hraw + b * NHID))[i];
    __syncthreads();
    if (!FIRST)
        att_inline<256>(hb, aux, (cc == 0) ? out1_prev + b * NHID : nullptr,
                        mq, mk, mv, mfc, mg, mb);
    // scores[h,q,kk] = hb[q-row] . KM[(b6+kk), h-slice]
    for (int id = tid; id < 288; id += 256) {
        int h = id / 36, r = id % 36, q = r / 6, kk = r % 6;
        const float4* qr = (const float4*)(hb + q * 200);
        const float4* kr = (const float4*)(KMt + (long)(b * 6 + kk) * L1D + h * 200);
        float s0 = 0, s1 = 0, s2 = 0, s3 = 0;
        #pragma unroll 5
        for (int d = 0; d < 50; d++) {
            float4 a = qr[d], v = kr[d];
            s0 += a.x * v.x; s1 += a.y * v.y; s2 += a.z * v.z; s3 += a.w * v.w;
        }
        attp[(h * 6 + q) * 6 + kk] = (s0 + s1 + s2 + s3) * 0.07071067811865475f;
    }
    __syncthreads();
    if (tid < 48) {
        float* a = attp + tid * 6;
        float mx = a[0];
        for (int i = 1; i < 6; i++) mx = fmaxf(mx, a[i]);
        float sm = 0;
        for (int i = 0; i < 6; i++) { a[i] = expf(a[i] - mx); sm += a[i]; }
        float inv = 1.f / sm;
        for (int i = 0; i < 6; i++) a[i] *= inv;
    }
    __syncthreads();
    // F slice: c0 = cc*300+tid, c1 = cc*300+256+tid (tid<44)
    const int cbase = cc * 300;
    const int c0 = cbase + tid;
    const bool has1 = tid < 44;
    const int c1 = cbase + 256 + tid;
    float f0[6] = {}, f1[6] = {};
    const float* vb0 = VFhc + (long)b * 48 * NINP;
    for (int kk = 0; kk < 6; kk++) {
        #pragma unroll 2
        for (int h = 0; h < 8; h++) {
            const float* vr = vb0 + (long)(kk * 8 + h) * NINP;
            float v0 = vr[c0];
            float v1 = has1 ? vr[c1] : 0.f;
            const float* pw = attp + h * 36 + kk;
            #pragma unroll
            for (int q = 0; q < 6; q++) {
                float w = pw[q * 6];
                f0[q] += w * v0;
                f1[q] += w * v1;
            }
        }
    }
    float s[6], s2[6];
    #pragma unroll
    for (int q = 0; q < 6; q++) {
        Fbuf[(long)(b * 6 + q) * NINP + c0] = f0[q];
        if (has1) Fbuf[(long)(b * 6 + q) * NINP + c1] = f1[q];
        s[q] = f0[q] + f1[q];
        s2[q] = f0[q] * f0[q] + f1[q] * f1[q];
    }
    for (int off = 32; off; off >>= 1) {
        #pragma unroll
        for (int q = 0; q < 6; q++) {
            s[q] += __shfl_down(s[q], off);
            s2[q] += __shfl_down(s2[q], off);
        }
    }
    int wid = tid >> 6, lane = tid & 63;
    if (lane == 0) {
        #pragma unroll
        for (int q = 0; q < 6; q++) { aw[wid * 6 + q] = s[q]; bw[wid * 6 + q] = s2[q]; }
    }
    __syncthreads();
    if (tid < 6) {
        float S = 0, S2 = 0;
        #pragma unroll
        for (int w = 0; w < 4; w++) { S += aw[w * 6 + tid]; S2 += bw[w * 6 + tid]; }
        pstat[((long)(b * 6 + tid) * 8 + cc) * 2]     = S;
        pstat[((long)(b * 6 + tid) * 8 + cc) * 2 + 1] = S2;
    }
}

// ---------------------------------------------------------------------------
// lstm1ln: blocks 0..299 = LSTM gates with LN applied at x-staging (from Fbuf
// + pstat). Blocks >=300: piggyback VFh GEMM tiles (z 4..7, t+1).
// ---------------------------------------------------------------------------
__global__ __launch_bounds__(512) void lstm1ln_kernel(
    const float* __restrict__ Fbuf, const float* __restrict__ pstat,
    const float* __restrict__ lgw, const float* __restrict__ lbw,
    const float* __restrict__ hprev, float* __restrict__ c_io,
    const float* __restrict__ Wi, const float* __restrict__ Wh,
    const float* __restrict__ bih, const float* __restrict__ bhh,
    float* __restrict__ h_out,
    const float* __restrict__ out0_next, const float* __restrict__ LVF,
    float* __restrict__ VFh_next)
{
    __shared__ float h_s[200 * 33];
    __shared__ float x_s[2][100 * 33];
    __shared__ float ps[12][128];
    __shared__ float mu_ln[32], rs_ln[32];
    const int blk = blockIdx.x, tid = threadIdx.x;
    if (blk >= 300) {
        int pid = blk - 300;
        int z = 4 + pid / 38, r = pid % 38, mt = r / 19, nt = r % 19;
        piggy_tile(h_s, tid, tid < 256, out0_next, LVF + (long)z * 200 * NINP,
                   VFh_next + (long)z * NINP, mt, nt);
        return;
    }
    const int k = blk % 6, jt = blk / 6;
    const int b = tid & 31, jg = (tid >> 5) & 3, kh = tid >> 7;
    const int j = jt * 4 + jg;

    if (tid < 32) {
        float S = 0, S2 = 0;
        int row = tid * 6 + k;
        #pragma unroll
        for (int c2 = 0; c2 < 8; c2++) {
            S  += pstat[((long)row * 8 + c2) * 2];
            S2 += pstat[((long)row * 8 + c2) * 2 + 1];
        }
        float mu = S / (float)NINP;
        mu_ln[tid] = mu;
        rs_ln[tid] = 1.0f / sqrtf(S2 / (float)NINP - mu * mu + 1e-5f);
    }
    __syncthreads();

    for (int idx = tid; idx < 1600; idx += 512) {
        int bb = idx / 50, m4 = idx % 50;
        float4 v = *(const float4*)&hprev[bb * NHID + k * BS + m4 * 4];
        h_s[(m4 * 4 + 0) * 33 + bb] = v.x;
        h_s[(m4 * 4 + 1) * 33 + bb] = v.y;
        h_s[(m4 * 4 + 2) * 33 + bb] = v.z;
        h_s[(m4 * 4 + 3) * 33 + bb] = v.w;
    }
    // stage x tile 0 with LN fold
    for (int idx = tid; idx < 800; idx += 512) {
        int bb = idx / 25, m4 = idx % 25;
        int c = m4 * 4;
        int row = bb * 6 + k;
        float4 f = *(const float4*)&Fbuf[(long)row * NINP + c];
        float4 g4 = *(const float4*)&lgw[c];
        float4 b4 = *(const float4*)&lbw[c];
        float mu = mu_ln[bb], rs = rs_ln[bb];
        x_s[0][(m4 * 4 + 0) * 33 + bb] = (f.x - mu) * rs * g4.x + b4.x;
        x_s[0][(m4 * 4 + 1) * 33 + bb] = (f.y - mu) * rs * g4.y + b4.y;
        x_s[0][(m4 * 4 + 2) * 33 + bb] = (f.z - mu) * rs * g4.z + b4.z;
        x_s[0][(m4 * 4 + 3) * 33 + bb] = (f.w - mu) * rs * g4.w + b4.w;
    }

    const float* wi0 = Wi + (long)(k * 800 + j) * NINP;
    const float* wi1 = wi0 + (long)200 * NINP;
    const float* wi2 = wi0 + (long)400 * NINP;
    const float* wi3 = wi0 + (long)600 * NINP;
    float a0 = 0, a1 = 0, a2 = 0, a3 = 0;
    int cur = 0;
    for (int ti = 0; ti < 24; ti++) {
        __syncthreads();
        if (ti + 1 < 24) {
            int kt = (ti + 1) * 100;
            float* xs = x_s[cur ^ 1];
            for (int idx = tid; idx < 800; idx += 512) {
                int bb = idx / 25, m4 = idx % 25;
                int c = kt + m4 * 4;
                int row = bb * 6 + k;
                float4 f = *(const float4*)&Fbuf[(long)row * NINP + c];
                float4 g4 = *(const float4*)&lgw[c];
                float4 b4 = *(const float4*)&lbw[c];
                float mu = mu_ln[bb], rs = rs_ln[bb];
                xs[(m4 * 4 + 0) * 33 + bb] = (f.x - mu) * rs * g4.x + b4.x;
                xs[(m4 * 4 + 1) * 33 + bb] = (f.y - mu) * rs * g4.y + b4.y;
                xs[(m4 * 4 + 2) * 33 + bb] = (f.z - mu) * rs * g4.z + b4.z;
                xs[(m4 * 4 + 3) * 33 + bb] = (f.w - mu) * rs * g4.w + b4.w;
            }
        }
        if (ti / 6 == kh) {
            const int kt = ti * 100;
            const float* xs = x_s[cur];
            for (int m = 0; m < 100; m += 4) {
                float4 w0 = *(const float4*)&wi0[kt + m];
                float4 w1 = *(const float4*)&wi1[kt + m];
                float4 w2 = *(const float4*)&wi2[kt + m];
                float4 w3 = *(const float4*)&wi3[kt + m];
                float x0 = xs[(m + 0) * 33 + b], x1 = xs[(m + 1) * 33 + b];
                float x2 = xs[(m + 2) * 33 + b], x3 = xs[(m + 3) * 33 + b];
                a0 += x0 * w0.x + x1 * w0.y + x2 * w0.z + x3 * w0.w;
                a1 += x0 * w1.x + x1 * w1.y + x2 * w1.z + x3 * w1.w;
                a2 += x0 * w2.x + x1 * w2.y + x2 * w2.z + x3 * w2.w;
                a3 += x0 * w3.x + x1 * w3.y + x2 * w3.z + x3 * w3.w;
            }
        }
        cur ^= 1;
    }
    if (kh == 0) {
        const float* w0 = Wh + (long)(k * 800 + j) * 200;
        const float* w1 = w0 + 200 * 200;
        const float* w2 = w0 + 400 * 200;
        const float* w3 = w0 + 600 * 200;
        for (int m = 0; m < 200; m += 4) {
            float4 wv0 = *(const float4*)&w0[m];
            float4 wv1 = *(const float4*)&w1[m];
            float4 wv2 = *(const float4*)&w2[m];
            float4 wv3 = *(const float4*)&w3[m];
            float h0v = h_s[(m + 0) * 33 + b], h1v = h_s[(m + 1) * 33 + b];
            float h2v = h_s[(m + 2) * 33 + b], h3v = h_s[(m + 3) * 33 + b];
            a0 += h0v * wv0.x + h1v * wv0.y + h2v * wv0.z + h3v * wv0.w;
            a1 += h0v * wv1.x + h1v * wv1.y + h2v * wv1.z + h3v * wv1.w;
            a2 += h0v * wv2.x + h1v * wv2.y + h2v * wv2.z + h3v * wv2.w;
            a3 += h0v * wv3.x + h1v * wv3.y + h2v * wv3.z + h3v * wv3.w;
        }
    } else {
        int g = (kh - 1) * 4, t2 = tid & 127;
        ps[g + 0][t2] = a0; ps[g + 1][t2] = a1; ps[g + 2][t2] = a2; ps[g + 3][t2] = a3;
    }
    __syncthreads();
    if (kh == 0) {
        a0 += ps[0][tid] + ps[4][tid] + ps[8][tid];
        a1 += ps[1][tid] + ps[5][tid] + ps[9][tid];
        a2 += ps[2][tid] + ps[6][tid] + ps[10][tid];
        a3 += ps[3][tid] + ps[7][tid] + ps[11][tid];
        int nb2 = k * 800;
        float gi = a0 + bih[nb2 + j] + bhh[nb2 + j];
        float gf = a1 + bih[nb2 + 200 + j] + bhh[nb2 + 200 + j];
        float gg = a2 + bih[nb2 + 400 + j] + bhh[nb2 + 400 + j];
        float go = a3 + bih[nb2 + 600 + j] + bhh[nb2 + 600 + j];
        int o = b * NHID + k * BS + j;
        float cold = c_io[o];
        float cn = sigmoidf_(gf) * cold + sigmoidf_(gi) * tanhf(gg);
        float hn = sigmoidf_(go) * tanhf(cn);
        c_io[o] = cn;
        h_out[o] = hn;
    }
}

// ---------------------------------------------------------------------------
// Standalone att_small (final out1[31]). grid = 32 (b).
// ---------------------------------------------------------------------------
__global__ __launch_bounds__(256) void attsmall_kernel(
    const float* __restrict__ h_in, float* __restrict__ h_out,
    const float* __restrict__ mq, const float* __restrict__ mk,
    const float* __restrict__ mv, const float* __restrict__ mfc,
    const float* __restrict__ mg, const float* __restrict__ mb)
{
    __shared__ __align__(16) float hb[1200];
    __shared__ __align__(16) float aux[2896];
    const int b = blockIdx.x, tid = threadIdx.x;
    for (int i = tid; i < 300; i += 256)
        ((float4*)hb)[i] = ((const float4*)(h_in + b * NHID))[i];
    __syncthreads();
    att_inline<256>(hb, aux, h_out + b * NHID, mq, mk, mv, mfc, mg, mb);
}

// ---------------------------------------------------------------------------
extern "C" void kernel_launch(void* const* d_in, const int* in_sizes, int n_in,
                              void* d_out, int out_size, void* d_ws, size_t ws_size,
                              hipStream_t stream)
{
    const int*   tokens = (const int*)  d_in[0];
    const float* h0     = (const float*)d_in[1];
    const float* c0     = (const float*)d_in[2];
    const float* emb    = (const float*)d_in[3];
    const float* Wi     = (const float*)d_in[4];
    const float* Wh     = (const float*)d_in[5];
    const float* bih    = (const float*)d_in[6];
    const float* bhh    = (const float*)d_in[7];
    const float* mq     = (const float*)d_in[8];
    const float* mk     = (const float*)d_in[9];
    const float* mv     = (const float*)d_in[10];
    const float* mfc    = (const float*)d_in[11];
    const float* mg     = (const float*)d_in[12];
    const float* mb     = (const float*)d_in[13];
    const float* lq     = (const float*)d_in[14];
    const float* lk     = (const float*)d_in[15];
    const float* lv     = (const float*)d_in[16];
    const float* lfc    = (const float*)d_in[17];
    const float* lg     = (const float*)d_in[18];
    const float* lb     = (const float*)d_in[19];
    const float* dec_w  = (const float*)d_in[20];
    const float* dec_b  = (const float*)d_in[21];
    float* out = (float*)d_out;

    // workspace carve-up (floats) — total ~121 MB (< 131 MB proven in round 4)
    float* p = (float*)d_ws;
    float* GX0   = p; p += (long)ROWS * NG;        // 4,915,200
    float* out0  = p; p += (long)ROWS * NHID;      // 1,228,800
    float* out1  = p; p += (long)ROWS * NHID;      // 1,228,800
    float* KM    = p; p += (long)ROWS * 6 * L1D;   // 9,830,400
    float* Fbuf  = p; p += 192 * NINP;             // 460,800
    float* pstat = p; p += 4096;                   // 192*8*2 used
    float* htmp  = p; p += BZ * NHID;
    float* cb1   = p; p += BZ * NHID;
    float* BigB  = p; p += 200 * L1D;
    float* WhT   = p; p += 6 * 200 * 800;
    float* LVF   = p; p += (long)8 * 200 * NINP;   // 3,840,000
    float* VFhC  = p; p += (long)2 * 192 * 8 * NINP; // 7,372,800 (2 slots)
    const long SLOT = (long)192 * 8 * NINP;        // 3,686,400 floats per slot

    long off = (long)ROWS * NTOK;
    float* cf0 = out + off + 2 * ST;

    hipMemcpyAsync(cb1, c0 + ST, ST * sizeof(float), hipMemcpyDeviceToDevice, stream);

    bigb_kernel<<<1250, 256, 0, stream>>>(lq, lk, BigB);
    whT_kernel<<<3750, 256, 0, stream>>>(Wh, WhT);

    // GX0 = emb[tokens] @ Wi^T + bih + bhh
    gemm128_kernel<true><<<dim3(NG / 128 + 1, ROWS / 128), 256, 0, stream>>>(
        emb, Wi, bih, bhh, GX0, ROWS, NG, NINP, tokens);

    // Phase A
    phaseA_kernel<<<BZ, 1024, 0, stream>>>(
        GX0, h0, c0, WhT, out0, cf0, mq, mk, mv, mfc, mg, mb);

    // KM = out0 @ BigB (Gram-projected keys)
    gemm128_kernel<false><<<dim3((L1D + 127) / 128, (ROWS * 6) / 128), 256, 0, stream>>>(
        out0, BigB, nullptr, nullptr, KM, ROWS * 6, L1D, BS, nullptr);

    // LVF[h] = lv_h (200x200) @ lfc_h (200x2400)
    gemmz_kernel<<<dim3((NINP + 127) / 128, 2, 8), 256, 0, stream>>>(
        lv, lfc, LVF, 200, NINP, 200,
        (long)L1D, 200L, (long)200 * NINP, (long)NINP, (long)200 * NINP);

    // bootstrap: VFhC slot 0 = out0(t=0 rows) @ LVF  (all 8 heads)
    gemmz_kernel<<<dim3((NINP + 127) / 128, 2, 8), 256, 0, stream>>>(
        out0, LVF, VFhC, 192, NINP, 200,
        200L, 0L, (long)200 * NINP, (long)8 * NINP, (long)NINP);

    // ---- Phase B: 2 launches per t, VFh GEMM for t+1 piggybacked ----
    for (int t = 0; t < TT; t++) {
        const float* hp = (t == 0) ? h0 + ST : out1 + (long)(t - 1) * ST;
        const float* KMt = KM + (long)t * BZ * 6 * L1D;
        const float* VFhc = VFhC + (long)(t & 1) * SLOT;
        const bool hasNext = (t + 1 < TT);
        const float* o0n = hasNext ? out0 + (long)(t + 1) * ST : nullptr;
        float* vfn = VFhC + (long)((t + 1) & 1) * SLOT;
        int gA = 256 + (hasNext ? 152 : 0);
        int gL = 300 + (hasNext ? 152 : 0);
        if (t == 0) {
            fusedattF_kernel<true><<<gA, 256, 0, stream>>>(
                h0 + ST, nullptr, KMt, VFhc, Fbuf, pstat,
                o0n, LVF, vfn, mq, mk, mv, mfc, mg, mb);
        } else {
            fusedattF_kernel<false><<<gA, 256, 0, stream>>>(
                htmp, out1 + (long)(t - 1) * ST, KMt, VFhc, Fbuf, pstat,
                o0n, LVF, vfn, mq, mk, mv, mfc, mg, mb);
        }
        lstm1ln_kernel<<<gL, 512, 0, stream>>>(
            Fbuf, pstat, lg, lb, hp, cb1, Wi, Wh, bih, bhh, htmp,
            o0n, LVF, vfn);
    }

    attsmall_kernel<<<BZ, 256, 0, stream>>>(htmp, out1 + (long)31 * ST, mq, mk, mv, mfc, mg, mb);

    // decode
    gemm128_kernel<true><<<dim3(NTOK / 128, ROWS / 128), 256, 0, stream>>>(
        out1, dec_w, dec_b, nullptr, out, ROWS, NTOK, NHID, nullptr);

    hipMemcpyAsync(out + off,          out0 + (long)31 * ST, ST * sizeof(float), hipMemcpyDeviceToDevice, stream);
    hipMemcpyAsync(out + off + ST,     out1 + (long)31 * ST, ST * sizeof(float), hipMemcpyDeviceToDevice, stream);
    hipMemcpyAsync(out + off + 3 * ST, cb1,                  ST * sizeof(float), hipMemcpyDeviceToDevice, stream);
}